// Round 1
// baseline (1239.347 us; speedup 1.0000x reference)
//
#include <hip/hip_runtime.h>
#include <hip/hip_bf16.h>
#include <stdint.h>

#define NNODES 50000
#define NEDGES 800000
#define DIN    2048
#define CDIM   256
#define ELOOP  (NEDGES + NNODES)   // edges + self loops

using bf16x8 = __attribute__((ext_vector_type(8))) short;
using f32x4  = __attribute__((ext_vector_type(4))) float;
using gvoid  = __attribute__((address_space(1))) const void;
using lvoid  = __attribute__((address_space(3))) void;

__device__ __forceinline__ float bf2f(uint16_t u) {
    union { uint32_t i; float f; } v; v.i = (uint32_t)u << 16; return v.f;
}
__device__ __forceinline__ uint16_t f2bf(float f) {
    union { float f; uint32_t i; } v; v.f = f;
    uint32_t i = v.i;
    return (uint16_t)((i + 0x7FFFu + ((i >> 16) & 1u)) >> 16);
}

#define BM 128
#define BN 128
#define BK 32

// ---------------------------------------------------------------- GEMM (bf16 A)
// C[M,N] = A[M,K] @ Bt[N,K]^T ; A,Bt,C bf16 row-major; bias fp32 optional.
// Double-buffered LDS staging: stage(t+1) issued BEFORE compute(t) so the
// vmcnt(0) drain at the barrier overlaps the MFMA phase.
__global__ __launch_bounds__(256)
void gemm_bt(const uint16_t* __restrict__ A, const uint16_t* __restrict__ Bt,
             uint16_t* __restrict__ C, const float* __restrict__ bias,
             int M, int N, int K)
{
    __shared__ __align__(16) uint16_t lA[2][BM * BK];   // 2 x 8 KB
    __shared__ __align__(16) uint16_t lB[2][BN * BK];   // 2 x 8 KB
    const int tid  = threadIdx.x;
    const int wave = tid >> 6;
    const int lane = tid & 63;
    const int lm = lane & 15, lq = lane >> 4;
    const int bm = blockIdx.x * BM;
    const int bn = blockIdx.y * BN;
    const int wm = (wave >> 1) * 64;
    const int wn = (wave & 1) * 64;

    f32x4 acc[4][4];
    for (int i = 0; i < 4; ++i)
        for (int j = 0; j < 4; ++j)
            acc[i][j] = (f32x4)0.0f;

    auto stage = [&](int buf, int k0) {
        for (int j = 0; j < 2; ++j) {           // A tile: 512 x 16B chunks
            int c = j * 256 + wave * 64 + lane;
            int row = c >> 2, cc = c & 3;
            int gr = bm + row; if (gr >= M) gr = M - 1;
            const uint16_t* gp = A + (size_t)gr * K + k0 + cc * 8;
            __builtin_amdgcn_global_load_lds((gvoid*)gp,
                (lvoid*)(lA[buf] + (size_t)(j * 256 + wave * 64) * 8), 16, 0, 0);
        }
        for (int j = 0; j < 2; ++j) {           // B tile
            int c = j * 256 + wave * 64 + lane;
            int row = c >> 2, cc = c & 3;
            int gr = bn + row; if (gr >= N) gr = N - 1;
            const uint16_t* gp = Bt + (size_t)gr * K + k0 + cc * 8;
            __builtin_amdgcn_global_load_lds((gvoid*)gp,
                (lvoid*)(lB[buf] + (size_t)(j * 256 + wave * 64) * 8), 16, 0, 0);
        }
    };

    const int nt = K / BK;
    stage(0, 0);
    __syncthreads();
    int cur = 0;
    for (int t = 0; t < nt; ++t) {
        if (t + 1 < nt) stage(cur ^ 1, (t + 1) * BK);

        bf16x8 af[4], bfr[4];
        for (int mt = 0; mt < 4; ++mt)
            af[mt] = *(const bf16x8*)(lA[cur] + (wm + mt * 16 + lm) * BK + lq * 8);
        for (int nt2 = 0; nt2 < 4; ++nt2)
            bfr[nt2] = *(const bf16x8*)(lB[cur] + (wn + nt2 * 16 + lm) * BK + lq * 8);

        for (int mt = 0; mt < 4; ++mt)
            for (int nt2 = 0; nt2 < 4; ++nt2)
                acc[mt][nt2] = __builtin_amdgcn_mfma_f32_16x16x32_bf16(
                    af[mt], bfr[nt2], acc[mt][nt2], 0, 0, 0);
        __syncthreads();        // drains vmcnt (stage t+1) + lgkm (ds_reads)
        cur ^= 1;
    }

    for (int mt = 0; mt < 4; ++mt) {
        for (int nt2 = 0; nt2 < 4; ++nt2) {
            int gn = bn + wn + nt2 * 16 + lm;
            float badd = bias ? bias[gn] : 0.0f;
            for (int r = 0; r < 4; ++r) {
                int gm = bm + wm + mt * 16 + lq * 4 + r;
                if (gm < M)
                    C[(size_t)gm * N + gn] = f2bf(acc[mt][nt2][r] + badd);
            }
        }
    }
}

// ---------------------------------------------------------------- GEMM (fp32 A)
// C[M,N] = A_f32[M,K] @ Bt_bf16[N,K]^T ; converts A tiles fp32->bf16 at
// fragment read. A tile rows are 128 B (bank-period) -> XOR chunk swizzle.
// Same double-buffered schedule as gemm_bt.
__global__ __launch_bounds__(256)
void gemm_f32_bt(const float* __restrict__ A, const uint16_t* __restrict__ Bt,
                 uint16_t* __restrict__ C, int M, int N, int K)
{
    __shared__ __align__(16) float    lA[2][BM * BK];   // 2 x 16 KB fp32
    __shared__ __align__(16) uint16_t lB[2][BN * BK];   // 2 x 8 KB bf16
    const int tid  = threadIdx.x;
    const int wave = tid >> 6;
    const int lane = tid & 63;
    const int lm = lane & 15, lq = lane >> 4;
    const int bm = blockIdx.x * BM;
    const int bn = blockIdx.y * BN;
    const int wm = (wave >> 1) * 64;
    const int wn = (wave & 1) * 64;

    f32x4 acc[4][4];
    for (int i = 0; i < 4; ++i)
        for (int j = 0; j < 4; ++j)
            acc[i][j] = (f32x4)0.0f;

    auto stage = [&](int buf, int k0) {
        // A tile fp32: 128 rows x 32 floats = 1024 x 16B chunks, XOR-swizzled
        for (int j = 0; j < 4; ++j) {
            int c = j * 256 + wave * 64 + lane;
            int row = c >> 3;                     // 8 chunks per row
            int lc  = (c & 7) ^ (row & 7);        // logical chunk in this slot
            int gr = bm + row; if (gr >= M) gr = M - 1;
            const float* gp = A + (size_t)gr * K + k0 + lc * 4;
            __builtin_amdgcn_global_load_lds((gvoid*)gp,
                (lvoid*)(lA[buf] + (size_t)(j * 256 + wave * 64) * 4), 16, 0, 0);
        }
        // B tile bf16: 512 x 16B chunks (m97 pattern, no swizzle)
        for (int j = 0; j < 2; ++j) {
            int c = j * 256 + wave * 64 + lane;
            int row = c >> 2, cc = c & 3;
            int gr = bn + row; if (gr >= N) gr = N - 1;
            const uint16_t* gp = Bt + (size_t)gr * K + k0 + cc * 8;
            __builtin_amdgcn_global_load_lds((gvoid*)gp,
                (lvoid*)(lB[buf] + (size_t)(j * 256 + wave * 64) * 8), 16, 0, 0);
        }
    };

    const int nt = K / BK;
    stage(0, 0);
    __syncthreads();
    int cur = 0;
    for (int t = 0; t < nt; ++t) {
        if (t + 1 < nt) stage(cur ^ 1, (t + 1) * BK);

        bf16x8 af[4], bfr[4];
        for (int mt = 0; mt < 4; ++mt) {
            int r = wm + mt * 16 + lm;
            int s0 = (lq * 2)     ^ (r & 7);
            int s1 = (lq * 2 + 1) ^ (r & 7);
            f32x4 a0 = *(const f32x4*)(lA[cur] + r * BK + s0 * 4);
            f32x4 a1 = *(const f32x4*)(lA[cur] + r * BK + s1 * 4);
            bf16x8 t2;
            for (int q = 0; q < 4; ++q) {
                t2[q]     = (short)f2bf(a0[q]);
                t2[q + 4] = (short)f2bf(a1[q]);
            }
            af[mt] = t2;
        }
        for (int nt2 = 0; nt2 < 4; ++nt2)
            bfr[nt2] = *(const bf16x8*)(lB[cur] + (wn + nt2 * 16 + lm) * BK + lq * 8);

        for (int mt = 0; mt < 4; ++mt)
            for (int nt2 = 0; nt2 < 4; ++nt2)
                acc[mt][nt2] = __builtin_amdgcn_mfma_f32_16x16x32_bf16(
                    af[mt], bfr[nt2], acc[mt][nt2], 0, 0, 0);
        __syncthreads();
        cur ^= 1;
    }

    for (int mt = 0; mt < 4; ++mt) {
        for (int nt2 = 0; nt2 < 4; ++nt2) {
            int gn = bn + wn + nt2 * 16 + lm;
            for (int r = 0; r < 4; ++r) {
                int gm = bm + wm + mt * 16 + lq * 4 + r;
                if (gm < M)
                    C[(size_t)gm * N + gn] = f2bf(acc[mt][nt2][r]);
            }
        }
    }
}

// ---------------------------------------------------------------- weight prep
// Wt_bf16[n*K + k] = (bf16) W_f32[k*N + n]
__global__ void transpose_cvt_kernel(const float* __restrict__ W,
                                     uint16_t* __restrict__ Wt, int K, int N)
{
    int idx = blockIdx.x * 256 + threadIdx.x;
    if (idx >= K * N) return;
    int n = idx / K, k = idx - n * K;
    Wt[idx] = f2bf(W[(size_t)k * N + n]);
}

// bias512[i] = (i<256) ? bp1[i] : 0
__global__ void bias512_kernel(const float* __restrict__ bp1,
                               float* __restrict__ bias512)
{
    int i = blockIdx.x * 256 + threadIdx.x;
    if (i < 512) bias512[i] = (i < 256) ? bp1[i] : 0.0f;
}

// ---------------------------------------------------------------- CSR build
__global__ void count_kernel(const int* __restrict__ ei, int* __restrict__ rs)
{
    int i = blockIdx.x * 256 + threadIdx.x;
    if (i >= ELOOP) return;
    int dst = (i < NEDGES) ? ei[NEDGES + i] : (i - NEDGES);
    atomicAdd(&rs[dst + 1], 1);
}

__global__ __launch_bounds__(1024)
void scan_kernel(int* __restrict__ rs, int* __restrict__ cursor)
{
    __shared__ int wsum[16];
    const int tid = threadIdx.x, lane = tid & 63, w = tid >> 6;
    int carry = 0;
    for (int base = 0; base <= NNODES; base += 1024) {
        int i = base + tid;
        int v = (i <= NNODES) ? rs[i] : 0;
        int s = v;
        for (int d = 1; d < 64; d <<= 1) {
            int t = __shfl_up(s, d);
            if (lane >= d) s += t;
        }
        if (lane == 63) wsum[w] = s;
        __syncthreads();
        if (tid < 16) {
            int x = wsum[tid];
            for (int d = 1; d < 16; d <<= 1) {
                int t = __shfl_up(x, d);
                if (tid >= d) x += t;
            }
            wsum[tid] = x;
        }
        __syncthreads();
        int incl = s + carry + (w > 0 ? wsum[w - 1] : 0);
        if (i <= NNODES) {
            rs[i] = incl;
            if (i < NNODES) cursor[i] = incl;
        }
        int total = carry + wsum[15];
        __syncthreads();
        carry = total;
    }
}

__global__ void fill_kernel(const int* __restrict__ ei, int* __restrict__ cursor,
                            int* __restrict__ csr_src)
{
    int i = blockIdx.x * 256 + threadIdx.x;
    if (i >= ELOOP) return;
    int src, dst;
    if (i < NEDGES) { src = ei[i]; dst = ei[NEDGES + i]; }
    else            { src = dst = i - NEDGES; }
    int pos = atomicAdd(&cursor[dst], 1);
    csr_src[pos] = src;
}

// ---------------------------------------------------------------- per-row dual dot
// s_src[n] = g[n,:]·a_src ; s_dst[n] = g[n,:]·a_dst  (g bf16, a fp32)
__global__ __launch_bounds__(256)
void rowdot_kernel(const uint16_t* __restrict__ g,
                   const float* __restrict__ asrc,
                   const float* __restrict__ adst,
                   float* __restrict__ s_src, float* __restrict__ s_dst)
{
    int n = blockIdx.x * 4 + (threadIdx.x >> 6);
    int lane = threadIdx.x & 63;
    ushort4 rv = *(const ushort4*)(g + (size_t)n * CDIM + lane * 4);
    float4 av = *(const float4*)(asrc + lane * 4);
    float4 dv = *(const float4*)(adst + lane * 4);
    float r0 = bf2f(rv.x), r1 = bf2f(rv.y), r2 = bf2f(rv.z), r3 = bf2f(rv.w);
    float a = r0 * av.x + r1 * av.y + r2 * av.z + r3 * av.w;
    float b = r0 * dv.x + r1 * dv.y + r2 * dv.z + r3 * dv.w;
    for (int d = 32; d; d >>= 1) { a += __shfl_xor(a, d); b += __shfl_xor(b, d); }
    if (lane == 0) { s_src[n] = a; s_dst[n] = b; }
}

// ---------------------------------------------------------------- GAT attention
__global__ __launch_bounds__(256)
void attn_kernel(const int* __restrict__ row_start, const int* __restrict__ csr_src,
                 const float* __restrict__ s_src, const float* __restrict__ s_dst,
                 const uint16_t* __restrict__ g, const float* __restrict__ bvec,
                 uint16_t* __restrict__ hout)
{
    int n = blockIdx.x * 4 + (threadIdx.x >> 6);
    int lane = threadIdx.x & 63;
    int beg = row_start[n], end = row_start[n + 1];
    float sdn = s_dst[n];

    float m = -1e30f;
    for (int i = beg + lane; i < end; i += 64) {
        float e = s_src[csr_src[i]] + sdn;
        e = (e > 0.f) ? e : 0.2f * e;
        m = fmaxf(m, e);
    }
    for (int d = 32; d; d >>= 1) m = fmaxf(m, __shfl_xor(m, d));

    float sum = 0.f;
    for (int i = beg + lane; i < end; i += 64) {
        float e = s_src[csr_src[i]] + sdn;
        e = (e > 0.f) ? e : 0.2f * e;
        sum += __expf(e - m);
    }
    for (int d = 32; d; d >>= 1) sum += __shfl_xor(sum, d);
    float inv = 1.f / (sum + 1e-16f);

    float a0 = 0.f, a1 = 0.f, a2 = 0.f, a3 = 0.f;
    for (int i = beg; i < end; ++i) {
        int src = csr_src[i];
        float e = s_src[src] + sdn;
        e = (e > 0.f) ? e : 0.2f * e;
        float alpha = __expf(e - m) * inv;
        ushort4 rv = *(const ushort4*)(g + (size_t)src * CDIM + lane * 4);
        a0 += alpha * bf2f(rv.x);
        a1 += alpha * bf2f(rv.y);
        a2 += alpha * bf2f(rv.z);
        a3 += alpha * bf2f(rv.w);
    }
    float4 bv = *(const float4*)(bvec + lane * 4);
    ushort4 o;
    o.x = f2bf(a0 + bv.x);
    o.y = f2bf(a1 + bv.y);
    o.z = f2bf(a2 + bv.z);
    o.w = f2bf(a3 + bv.w);
    *(ushort4*)(hout + (size_t)n * CDIM + lane * 4) = o;
}

// ---------------------------------------------------------------- edge predictor
// out[e] = relu(U[src]+V[dst]) · wp2 + bp2 ; U,V interleaved in UV[n][512]
// (U = cols 0..255 with bp1 folded in; V = cols 256..511)
__global__ __launch_bounds__(256)
void edgepred_kernel(const int* __restrict__ ei,
                     const uint16_t* __restrict__ UV,
                     const float* __restrict__ wp2, const float* __restrict__ bp2,
                     float* __restrict__ out)
{
    const int tid = threadIdx.x;
    const int grp = tid >> 4, l = tid & 15;
    const int e = blockIdx.x * 16 + grp;
    int src = ei[e];
    int dst = ei[NEDGES + e];
    const uint16_t* Up = UV + (size_t)src * 512 + l * 16;
    const uint16_t* Vp = UV + (size_t)dst * 512 + 256 + l * 16;
    const uint4 u0 = *(const uint4*)(Up);
    const uint4 u1 = *(const uint4*)(Up + 8);
    const uint4 v0 = *(const uint4*)(Vp);
    const uint4 v1 = *(const uint4*)(Vp + 8);
    const float4 w0 = *(const float4*)(wp2 + l * 16);
    const float4 w1 = *(const float4*)(wp2 + l * 16 + 4);
    const float4 w2 = *(const float4*)(wp2 + l * 16 + 8);
    const float4 w3 = *(const float4*)(wp2 + l * 16 + 12);
    float acc = 0.f;
    auto proc = [&](uint32_t uu, uint32_t vv, float wa, float wb) {
        float z0 = fmaxf(bf2f((uint16_t)(uu & 0xffffu)) + bf2f((uint16_t)(vv & 0xffffu)), 0.f);
        float z1 = fmaxf(bf2f((uint16_t)(uu >> 16)) + bf2f((uint16_t)(vv >> 16)), 0.f);
        acc += z0 * wa + z1 * wb;
    };
    proc(u0.x, v0.x, w0.x, w0.y); proc(u0.y, v0.y, w0.z, w0.w);
    proc(u0.z, v0.z, w1.x, w1.y); proc(u0.w, v0.w, w1.z, w1.w);
    proc(u1.x, v1.x, w2.x, w2.y); proc(u1.y, v1.y, w2.z, w2.w);
    proc(u1.z, v1.z, w3.x, w3.y); proc(u1.w, v1.w, w3.z, w3.w);
    for (int d = 1; d < 16; d <<= 1) acc += __shfl_xor(acc, d);
    if (l == 0) out[e] = acc + *bp2;
}

// ---------------------------------------------------------------- launch
extern "C" void kernel_launch(void* const* d_in, const int* in_sizes, int n_in,
                              void* d_out, int out_size, void* d_ws, size_t ws_size,
                              hipStream_t stream)
{
    const float* x   = (const float*)d_in[0];
    const int*   ei  = (const int*)d_in[1];
    const float* W1  = (const float*)d_in[2];
    const float* as1 = (const float*)d_in[3];
    const float* ad1 = (const float*)d_in[4];
    const float* b1  = (const float*)d_in[5];
    const float* W2  = (const float*)d_in[6];
    const float* as2 = (const float*)d_in[7];
    const float* ad2 = (const float*)d_in[8];
    const float* b2  = (const float*)d_in[9];
    const float* Wp1 = (const float*)d_in[10];
    const float* bp1 = (const float*)d_in[11];
    const float* wp2 = (const float*)d_in[12];
    const float* bp2 = (const float*)d_in[13];
    float* out = (float*)d_out;

    char* ws = (char*)d_ws;
    size_t off = 0;
    auto alloc = [&](size_t bytes) -> void* {
        void* p = ws + off;
        off += (bytes + 255) & ~(size_t)255;
        return p;
    };
    uint16_t* W1t   = (uint16_t*)alloc((size_t)DIN * CDIM * 2);
    uint16_t* W2t   = (uint16_t*)alloc((size_t)CDIM * CDIM * 2);
    uint16_t* WpABt = (uint16_t*)alloc((size_t)2 * CDIM * CDIM * 2); // 512x256 stacked
    int* row_start = (int*)alloc((NNODES + 1) * sizeof(int));
    int* cursor    = (int*)alloc(NNODES * sizeof(int));
    int* csr_src   = (int*)alloc((size_t)ELOOP * sizeof(int));
    float* s_src   = (float*)alloc(NNODES * sizeof(float));
    float* s_dst   = (float*)alloc(NNODES * sizeof(float));
    float* bias512 = (float*)alloc(512 * sizeof(float));
    uint16_t* H    = (uint16_t*)alloc((size_t)NNODES * CDIM * 2);  // h1 / h2
    uint16_t* G    = (uint16_t*)alloc((size_t)NNODES * CDIM * 2);  // lin out
    uint16_t* Vb   = (uint16_t*)alloc((size_t)NNODES * CDIM * 2);  // adjacent to G
    // UV[50000][512] overlays G+Vb (both free at edge-predictor time;
    // NNODES*CDIM*2 = 25.6e6 is 256-aligned so Vb == G + 25.6e6).
    uint16_t* UV   = G;

    hipMemsetAsync(row_start, 0, (NNODES + 1) * sizeof(int), stream);

    transpose_cvt_kernel<<<(DIN * CDIM + 255) / 256, 256, 0, stream>>>(W1, W1t, DIN, CDIM);
    transpose_cvt_kernel<<<(CDIM * CDIM + 255) / 256, 256, 0, stream>>>(W2, W2t, CDIM, CDIM);
    transpose_cvt_kernel<<<(CDIM * CDIM + 255) / 256, 256, 0, stream>>>(Wp1, WpABt, CDIM, CDIM);
    transpose_cvt_kernel<<<(CDIM * CDIM + 255) / 256, 256, 0, stream>>>(Wp1 + CDIM * CDIM, WpABt + CDIM * CDIM, CDIM, CDIM);
    bias512_kernel<<<2, 256, 0, stream>>>(bp1, bias512);

    count_kernel<<<(ELOOP + 255) / 256, 256, 0, stream>>>(ei, row_start);
    scan_kernel<<<1, 1024, 0, stream>>>(row_start, cursor);
    fill_kernel<<<(ELOOP + 255) / 256, 256, 0, stream>>>(ei, cursor, csr_src);

    dim3 gg((NNODES + BM - 1) / BM, CDIM / BN);

    // layer 1: h1_lin = x @ W1  (fp32 A path)
    gemm_f32_bt<<<gg, 256, 0, stream>>>(x, W1t, G, NNODES, CDIM, DIN);
    rowdot_kernel<<<NNODES / 4, 256, 0, stream>>>(G, as1, ad1, s_src, s_dst);
    attn_kernel<<<NNODES / 4, 256, 0, stream>>>(row_start, csr_src, s_src, s_dst, G, b1, H);

    // layer 2
    gemm_bt<<<gg, 256, 0, stream>>>(H, W2t, G, nullptr, NNODES, CDIM, CDIM);
    rowdot_kernel<<<NNODES / 4, 256, 0, stream>>>(G, as2, ad2, s_src, s_dst);
    attn_kernel<<<NNODES / 4, 256, 0, stream>>>(row_start, csr_src, s_src, s_dst, G, b2, H);

    // edge predictor: UV = h2 @ [WpA | WpB]  (single N=512 GEMM, bias [bp1,0])
    dim3 gg2((NNODES + BM - 1) / BM, 512 / BN);
    gemm_bt<<<gg2, 256, 0, stream>>>(H, WpABt, UV, bias512, NNODES, 512, CDIM);

    edgepred_kernel<<<NEDGES / 16, 256, 0, stream>>>(ei, UV, wp2, bp2, out);
}

// Round 2
// 1146.316 us; speedup vs baseline: 1.0812x; 1.0812x over previous
//
#include <hip/hip_runtime.h>
#include <hip/hip_bf16.h>
#include <stdint.h>

#define NNODES 50000
#define NEDGES 800000
#define DIN    2048
#define CDIM   256
#define ELOOP  (NEDGES + NNODES)   // edges + self loops

using bf16x8 = __attribute__((ext_vector_type(8))) short;
using f32x4  = __attribute__((ext_vector_type(4))) float;
using gvoid  = __attribute__((address_space(1))) const void;
using lvoid  = __attribute__((address_space(3))) void;

__device__ __forceinline__ float bf2f(uint16_t u) {
    union { uint32_t i; float f; } v; v.i = (uint32_t)u << 16; return v.f;
}
__device__ __forceinline__ uint16_t f2bf(float f) {
    union { float f; uint32_t i; } v; v.f = f;
    uint32_t i = v.i;
    return (uint16_t)((i + 0x7FFFu + ((i >> 16) & 1u)) >> 16);
}

#define BM 128
#define BN 128
#define BK 32

#define WAITVM(N) asm volatile("s_waitcnt vmcnt(" #N ")" ::: "memory")

// ---------------------------------------------------------------- GEMM (bf16 A)
// C[M,N] = A[M,K] @ Bt[N,K]^T ; A,Bt,C bf16 row-major; bias fp32 optional.
// Depth-2 pipeline: 3 LDS buffers, counted vmcnt (4 loads/stage/wave),
// raw s_barrier (no vmcnt(0) drain in steady state).
__global__ __launch_bounds__(256)
void gemm_bt(const uint16_t* __restrict__ A, const uint16_t* __restrict__ Bt,
             uint16_t* __restrict__ C, const float* __restrict__ bias,
             int M, int N, int K)
{
    __shared__ __align__(16) uint16_t lA[3][BM * BK];   // 3 x 8 KB
    __shared__ __align__(16) uint16_t lB[3][BN * BK];   // 3 x 8 KB
    const int tid  = threadIdx.x;
    const int wave = tid >> 6;
    const int lane = tid & 63;
    const int lm = lane & 15, lq = lane >> 4;
    const int bm = blockIdx.x * BM;
    const int bn = blockIdx.y * BN;
    const int wm = (wave >> 1) * 64;
    const int wn = (wave & 1) * 64;

    f32x4 acc[4][4];
    for (int i = 0; i < 4; ++i)
        for (int j = 0; j < 4; ++j)
            acc[i][j] = (f32x4)0.0f;

    auto stage = [&](int buf, int k0) {          // 4 global_load_lds per wave
        for (int j = 0; j < 2; ++j) {            // A tile: 512 x 16B chunks
            int c = j * 256 + wave * 64 + lane;
            int row = c >> 2, cc = c & 3;
            int gr = bm + row; if (gr >= M) gr = M - 1;
            const uint16_t* gp = A + (size_t)gr * K + k0 + cc * 8;
            __builtin_amdgcn_global_load_lds((gvoid*)gp,
                (lvoid*)(lA[buf] + (size_t)(j * 256 + wave * 64) * 8), 16, 0, 0);
        }
        for (int j = 0; j < 2; ++j) {            // B tile
            int c = j * 256 + wave * 64 + lane;
            int row = c >> 2, cc = c & 3;
            const uint16_t* gp = Bt + (size_t)(bn + row) * K + k0 + cc * 8;
            __builtin_amdgcn_global_load_lds((gvoid*)gp,
                (lvoid*)(lB[buf] + (size_t)(j * 256 + wave * 64) * 8), 16, 0, 0);
        }
    };

    const int ntiles = K / BK;                   // >= 2 always (K >= 256)
    stage(0, 0);
    stage(1, BK);
    WAITVM(4);                                   // tile 0 landed (own 4 oldest)
    __builtin_amdgcn_s_barrier();

    for (int t = 0; t < ntiles; ++t) {
        const int cur = t % 3;
        if (t + 2 < ntiles) stage((t + 2) % 3, (t + 2) * BK);

        bf16x8 af[4], bfr[4];
        for (int mt = 0; mt < 4; ++mt)
            af[mt] = *(const bf16x8*)(lA[cur] + (wm + mt * 16 + lm) * BK + lq * 8);
        for (int nt2 = 0; nt2 < 4; ++nt2)
            bfr[nt2] = *(const bf16x8*)(lB[cur] + (wn + nt2 * 16 + lm) * BK + lq * 8);

        for (int mt = 0; mt < 4; ++mt)
            for (int nt2 = 0; nt2 < 4; ++nt2)
                acc[mt][nt2] = __builtin_amdgcn_mfma_f32_16x16x32_bf16(
                    af[mt], bfr[nt2], acc[mt][nt2], 0, 0, 0);

        if (t + 1 < ntiles) {
            if (t + 2 < ntiles) WAITVM(4);       // tile t+1 done, t+2 in flight
            else                WAITVM(0);       // tail: drain last tile
            __builtin_amdgcn_s_barrier();
        }
    }

    for (int mt = 0; mt < 4; ++mt) {
        for (int nt2 = 0; nt2 < 4; ++nt2) {
            int gn = bn + wn + nt2 * 16 + lm;
            float badd = bias ? bias[gn] : 0.0f;
            for (int r = 0; r < 4; ++r) {
                int gm = bm + wm + mt * 16 + lq * 4 + r;
                if (gm < M)
                    C[(size_t)gm * N + gn] = f2bf(acc[mt][nt2][r] + badd);
            }
        }
    }
}

// ---------------------------------------------------------------- GEMM (fp32 A)
// C[M,N] = A_f32[M,K] @ Bt_bf16[N,K]^T ; fp32->bf16 at fragment read.
// A tile rows are 128 B (bank-period) -> XOR chunk swizzle.
// Same depth-2 pipeline (6 loads/stage/wave).
__global__ __launch_bounds__(256)
void gemm_f32_bt(const float* __restrict__ A, const uint16_t* __restrict__ Bt,
                 uint16_t* __restrict__ C, int M, int N, int K)
{
    __shared__ __align__(16) float    lA[3][BM * BK];   // 3 x 16 KB fp32
    __shared__ __align__(16) uint16_t lB[3][BN * BK];   // 3 x 8 KB bf16
    const int tid  = threadIdx.x;
    const int wave = tid >> 6;
    const int lane = tid & 63;
    const int lm = lane & 15, lq = lane >> 4;
    const int bm = blockIdx.x * BM;
    const int bn = blockIdx.y * BN;
    const int wm = (wave >> 1) * 64;
    const int wn = (wave & 1) * 64;

    f32x4 acc[4][4];
    for (int i = 0; i < 4; ++i)
        for (int j = 0; j < 4; ++j)
            acc[i][j] = (f32x4)0.0f;

    auto stage = [&](int buf, int k0) {          // 6 global_load_lds per wave
        for (int j = 0; j < 4; ++j) {            // A fp32: 1024 x 16B, swizzled
            int c = j * 256 + wave * 64 + lane;
            int row = c >> 3;                    // 8 chunks per row
            int lc  = (c & 7) ^ (row & 7);
            int gr = bm + row; if (gr >= M) gr = M - 1;
            const float* gp = A + (size_t)gr * K + k0 + lc * 4;
            __builtin_amdgcn_global_load_lds((gvoid*)gp,
                (lvoid*)(lA[buf] + (size_t)(j * 256 + wave * 64) * 4), 16, 0, 0);
        }
        for (int j = 0; j < 2; ++j) {            // B bf16: 512 x 16B
            int c = j * 256 + wave * 64 + lane;
            int row = c >> 2, cc = c & 3;
            const uint16_t* gp = Bt + (size_t)(bn + row) * K + k0 + cc * 8;
            __builtin_amdgcn_global_load_lds((gvoid*)gp,
                (lvoid*)(lB[buf] + (size_t)(j * 256 + wave * 64) * 8), 16, 0, 0);
        }
    };

    const int ntiles = K / BK;
    stage(0, 0);
    stage(1, BK);
    WAITVM(6);
    __builtin_amdgcn_s_barrier();

    for (int t = 0; t < ntiles; ++t) {
        const int cur = t % 3;
        if (t + 2 < ntiles) stage((t + 2) % 3, (t + 2) * BK);

        bf16x8 af[4], bfr[4];
        for (int mt = 0; mt < 4; ++mt) {
            int r = wm + mt * 16 + lm;
            int s0 = (lq * 2)     ^ (r & 7);
            int s1 = (lq * 2 + 1) ^ (r & 7);
            f32x4 a0 = *(const f32x4*)(lA[cur] + r * BK + s0 * 4);
            f32x4 a1 = *(const f32x4*)(lA[cur] + r * BK + s1 * 4);
            bf16x8 t2;
            for (int q = 0; q < 4; ++q) {
                t2[q]     = (short)f2bf(a0[q]);
                t2[q + 4] = (short)f2bf(a1[q]);
            }
            af[mt] = t2;
        }
        for (int nt2 = 0; nt2 < 4; ++nt2)
            bfr[nt2] = *(const bf16x8*)(lB[cur] + (wn + nt2 * 16 + lm) * BK + lq * 8);

        for (int mt = 0; mt < 4; ++mt)
            for (int nt2 = 0; nt2 < 4; ++nt2)
                acc[mt][nt2] = __builtin_amdgcn_mfma_f32_16x16x32_bf16(
                    af[mt], bfr[nt2], acc[mt][nt2], 0, 0, 0);

        if (t + 1 < ntiles) {
            if (t + 2 < ntiles) WAITVM(6);
            else                WAITVM(0);
            __builtin_amdgcn_s_barrier();
        }
    }

    for (int mt = 0; mt < 4; ++mt) {
        for (int nt2 = 0; nt2 < 4; ++nt2) {
            int gn = bn + wn + nt2 * 16 + lm;
            for (int r = 0; r < 4; ++r) {
                int gm = bm + wm + mt * 16 + lq * 4 + r;
                if (gm < M)
                    C[(size_t)gm * N + gn] = f2bf(acc[mt][nt2][r]);
            }
        }
    }
}

// ---------------------------------------------------------------- weight prep
// Wt_bf16[n*K + k] = (bf16) W_f32[k*N + n] ; tiled via LDS (coalesced both sides)
__global__ __launch_bounds__(256)
void transpose_cvt_kernel(const float* __restrict__ W,
                          uint16_t* __restrict__ Wt, int K, int N)
{
    __shared__ float tile[32][33];
    const int k0 = blockIdx.x * 32, n0 = blockIdx.y * 32;
    const int tx = threadIdx.x & 31, ty = threadIdx.x >> 5;   // 32x8
    for (int r = 0; r < 32; r += 8)
        tile[ty + r][tx] = W[(size_t)(k0 + ty + r) * N + n0 + tx];
    __syncthreads();
    for (int r = 0; r < 32; r += 8)
        Wt[(size_t)(n0 + ty + r) * K + k0 + tx] = f2bf(tile[tx][ty + r]);
}

// bias512[i] = (i<256) ? bp1[i] : 0
__global__ void bias512_kernel(const float* __restrict__ bp1,
                               float* __restrict__ bias512)
{
    int i = blockIdx.x * 256 + threadIdx.x;
    if (i < 512) bias512[i] = (i < 256) ? bp1[i] : 0.0f;
}

// ---------------------------------------------------------------- CSR build
__global__ void count_kernel(const int* __restrict__ ei, int* __restrict__ rs)
{
    int i = blockIdx.x * 256 + threadIdx.x;
    if (i >= ELOOP) return;
    int dst = (i < NEDGES) ? ei[NEDGES + i] : (i - NEDGES);
    atomicAdd(&rs[dst + 1], 1);
}

// parallel scan over rs[0..NNODES]: 49 blocks x 1024
__global__ __launch_bounds__(1024)
void scan_part_kernel(int* __restrict__ rs, int* __restrict__ bsum)
{
    __shared__ int wsum[16];
    const int b = blockIdx.x, tid = threadIdx.x, lane = tid & 63, w = tid >> 6;
    int i = b * 1024 + tid;
    int v = (i <= NNODES) ? rs[i] : 0;
    int s = v;
    for (int d = 1; d < 64; d <<= 1) {
        int t = __shfl_up(s, d);
        if (lane >= d) s += t;
    }
    if (lane == 63) wsum[w] = s;
    __syncthreads();
    if (tid < 16) {
        int x = wsum[tid];
        for (int d = 1; d < 16; d <<= 1) {
            int t = __shfl_up(x, d);
            if (tid >= d) x += t;
        }
        wsum[tid] = x;
    }
    __syncthreads();
    int incl = s + (w > 0 ? wsum[w - 1] : 0);
    if (i <= NNODES) rs[i] = incl;
    if (tid == 1023) bsum[b] = incl;      // chunk total (padding adds 0)
}

__global__ void scan_bsum_kernel(int* __restrict__ bsum, int nb)
{
    int tid = threadIdx.x;                 // 64 threads, nb <= 64
    int v = (tid < nb) ? bsum[tid] : 0;
    for (int d = 1; d < 64; d <<= 1) {
        int t = __shfl_up(v, d);
        if (tid >= d) v += t;
    }
    if (tid < nb) bsum[tid] = v;           // inclusive block prefix
}

__global__ __launch_bounds__(1024)
void scan_add_kernel(const int* __restrict__ bsum, int* __restrict__ rs,
                     int* __restrict__ cursor)
{
    int b = blockIdx.x;
    int i = b * 1024 + threadIdx.x;
    int add = b ? bsum[b - 1] : 0;
    if (i <= NNODES) {
        int r = rs[i] + add;
        rs[i] = r;
        if (i < NNODES) cursor[i] = r;
    }
}

__global__ void fill_kernel(const int* __restrict__ ei, int* __restrict__ cursor,
                            int* __restrict__ csr_src)
{
    int i = blockIdx.x * 256 + threadIdx.x;
    if (i >= ELOOP) return;
    int src, dst;
    if (i < NEDGES) { src = ei[i]; dst = ei[NEDGES + i]; }
    else            { src = dst = i - NEDGES; }
    int pos = atomicAdd(&cursor[dst], 1);
    csr_src[pos] = src;
}

// ---------------------------------------------------------------- per-row dual dot
__global__ __launch_bounds__(256)
void rowdot_kernel(const uint16_t* __restrict__ g,
                   const float* __restrict__ asrc,
                   const float* __restrict__ adst,
                   float* __restrict__ s_src, float* __restrict__ s_dst)
{
    int n = blockIdx.x * 4 + (threadIdx.x >> 6);
    int lane = threadIdx.x & 63;
    ushort4 rv = *(const ushort4*)(g + (size_t)n * CDIM + lane * 4);
    float4 av = *(const float4*)(asrc + lane * 4);
    float4 dv = *(const float4*)(adst + lane * 4);
    float r0 = bf2f(rv.x), r1 = bf2f(rv.y), r2 = bf2f(rv.z), r3 = bf2f(rv.w);
    float a = r0 * av.x + r1 * av.y + r2 * av.z + r3 * av.w;
    float b = r0 * dv.x + r1 * dv.y + r2 * dv.z + r3 * dv.w;
    for (int d = 32; d; d >>= 1) { a += __shfl_xor(a, d); b += __shfl_xor(b, d); }
    if (lane == 0) { s_src[n] = a; s_dst[n] = b; }
}

// ---------------------------------------------------------------- GAT attention
// one node per wave; weighted-gather loop processes 2 edges/iter via 32-lane
// half-waves (16B/lane) -> half the serial chain, 2x gathers in flight.
__global__ __launch_bounds__(256)
void attn_kernel(const int* __restrict__ row_start, const int* __restrict__ csr_src,
                 const float* __restrict__ s_src, const float* __restrict__ s_dst,
                 const uint16_t* __restrict__ g, const float* __restrict__ bvec,
                 uint16_t* __restrict__ hout)
{
    int n = blockIdx.x * 4 + (threadIdx.x >> 6);
    int lane = threadIdx.x & 63;
    int h = lane >> 5, hl = lane & 31;
    int beg = row_start[n], end = row_start[n + 1];
    float sdn = s_dst[n];

    float m = -1e30f;
    for (int i = beg + lane; i < end; i += 64) {
        float e = s_src[csr_src[i]] + sdn;
        e = (e > 0.f) ? e : 0.2f * e;
        m = fmaxf(m, e);
    }
    for (int d = 32; d; d >>= 1) m = fmaxf(m, __shfl_xor(m, d));

    float sum = 0.f;
    for (int i = beg + lane; i < end; i += 64) {
        float e = s_src[csr_src[i]] + sdn;
        e = (e > 0.f) ? e : 0.2f * e;
        sum += __expf(e - m);
    }
    for (int d = 32; d; d >>= 1) sum += __shfl_xor(sum, d);
    float inv = 1.f / (sum + 1e-16f);

    float a0 = 0.f, a1 = 0.f, a2 = 0.f, a3 = 0.f;
    float a4 = 0.f, a5 = 0.f, a6 = 0.f, a7 = 0.f;
    for (int i = beg + h; i < end; i += 2) {
        int src = csr_src[i];
        float e = s_src[src] + sdn;
        e = (e > 0.f) ? e : 0.2f * e;
        float alpha = __expf(e - m) * inv;
        uint4 rv = *(const uint4*)(g + (size_t)src * CDIM + hl * 8);
        a0 += alpha * bf2f((uint16_t)(rv.x & 0xffffu));
        a1 += alpha * bf2f((uint16_t)(rv.x >> 16));
        a2 += alpha * bf2f((uint16_t)(rv.y & 0xffffu));
        a3 += alpha * bf2f((uint16_t)(rv.y >> 16));
        a4 += alpha * bf2f((uint16_t)(rv.z & 0xffffu));
        a5 += alpha * bf2f((uint16_t)(rv.z >> 16));
        a6 += alpha * bf2f((uint16_t)(rv.w & 0xffffu));
        a7 += alpha * bf2f((uint16_t)(rv.w >> 16));
    }
    a0 += __shfl_xor(a0, 32); a1 += __shfl_xor(a1, 32);
    a2 += __shfl_xor(a2, 32); a3 += __shfl_xor(a3, 32);
    a4 += __shfl_xor(a4, 32); a5 += __shfl_xor(a5, 32);
    a6 += __shfl_xor(a6, 32); a7 += __shfl_xor(a7, 32);

    if (h == 0) {
        const float4 b0 = *(const float4*)(bvec + hl * 8);
        const float4 b1 = *(const float4*)(bvec + hl * 8 + 4);
        uint4 o;
        o.x = (uint32_t)f2bf(a0 + b0.x) | ((uint32_t)f2bf(a1 + b0.y) << 16);
        o.y = (uint32_t)f2bf(a2 + b0.z) | ((uint32_t)f2bf(a3 + b0.w) << 16);
        o.z = (uint32_t)f2bf(a4 + b1.x) | ((uint32_t)f2bf(a5 + b1.y) << 16);
        o.w = (uint32_t)f2bf(a6 + b1.z) | ((uint32_t)f2bf(a7 + b1.w) << 16);
        *(uint4*)(hout + (size_t)n * CDIM + hl * 8) = o;
    }
}

// ---------------------------------------------------------------- edge predictor
__global__ __launch_bounds__(256)
void edgepred_kernel(const int* __restrict__ ei,
                     const uint16_t* __restrict__ UV,
                     const float* __restrict__ wp2, const float* __restrict__ bp2,
                     float* __restrict__ out)
{
    const int tid = threadIdx.x;
    const int grp = tid >> 4, l = tid & 15;
    const int e = blockIdx.x * 16 + grp;
    int src = ei[e];
    int dst = ei[NEDGES + e];
    const uint16_t* Up = UV + (size_t)src * 512 + l * 16;
    const uint16_t* Vp = UV + (size_t)dst * 512 + 256 + l * 16;
    const uint4 u0 = *(const uint4*)(Up);
    const uint4 u1 = *(const uint4*)(Up + 8);
    const uint4 v0 = *(const uint4*)(Vp);
    const uint4 v1 = *(const uint4*)(Vp + 8);
    const float4 w0 = *(const float4*)(wp2 + l * 16);
    const float4 w1 = *(const float4*)(wp2 + l * 16 + 4);
    const float4 w2 = *(const float4*)(wp2 + l * 16 + 8);
    const float4 w3 = *(const float4*)(wp2 + l * 16 + 12);
    float acc = 0.f;
    auto proc = [&](uint32_t uu, uint32_t vv, float wa, float wb) {
        float z0 = fmaxf(bf2f((uint16_t)(uu & 0xffffu)) + bf2f((uint16_t)(vv & 0xffffu)), 0.f);
        float z1 = fmaxf(bf2f((uint16_t)(uu >> 16)) + bf2f((uint16_t)(vv >> 16)), 0.f);
        acc += z0 * wa + z1 * wb;
    };
    proc(u0.x, v0.x, w0.x, w0.y); proc(u0.y, v0.y, w0.z, w0.w);
    proc(u0.z, v0.z, w1.x, w1.y); proc(u0.w, v0.w, w1.z, w1.w);
    proc(u1.x, v1.x, w2.x, w2.y); proc(u1.y, v1.y, w2.z, w2.w);
    proc(u1.z, v1.z, w3.x, w3.y); proc(u1.w, v1.w, w3.z, w3.w);
    for (int d = 1; d < 16; d <<= 1) acc += __shfl_xor(acc, d);
    if (l == 0) out[e] = acc + *bp2;
}

// ---------------------------------------------------------------- launch
extern "C" void kernel_launch(void* const* d_in, const int* in_sizes, int n_in,
                              void* d_out, int out_size, void* d_ws, size_t ws_size,
                              hipStream_t stream)
{
    const float* x   = (const float*)d_in[0];
    const int*   ei  = (const int*)d_in[1];
    const float* W1  = (const float*)d_in[2];
    const float* as1 = (const float*)d_in[3];
    const float* ad1 = (const float*)d_in[4];
    const float* b1  = (const float*)d_in[5];
    const float* W2  = (const float*)d_in[6];
    const float* as2 = (const float*)d_in[7];
    const float* ad2 = (const float*)d_in[8];
    const float* b2  = (const float*)d_in[9];
    const float* Wp1 = (const float*)d_in[10];
    const float* bp1 = (const float*)d_in[11];
    const float* wp2 = (const float*)d_in[12];
    const float* bp2 = (const float*)d_in[13];
    float* out = (float*)d_out;

    char* ws = (char*)d_ws;
    size_t off = 0;
    auto alloc = [&](size_t bytes) -> void* {
        void* p = ws + off;
        off += (bytes + 255) & ~(size_t)255;
        return p;
    };
    uint16_t* W1t   = (uint16_t*)alloc((size_t)DIN * CDIM * 2);
    uint16_t* W2t   = (uint16_t*)alloc((size_t)CDIM * CDIM * 2);
    uint16_t* WpABt = (uint16_t*)alloc((size_t)2 * CDIM * CDIM * 2); // 512x256 stacked
    int* row_start = (int*)alloc((NNODES + 1) * sizeof(int));
    int* cursor    = (int*)alloc(NNODES * sizeof(int));
    int* csr_src   = (int*)alloc((size_t)ELOOP * sizeof(int));
    int* bsum      = (int*)alloc(64 * sizeof(int));
    float* s_src   = (float*)alloc(NNODES * sizeof(float));
    float* s_dst   = (float*)alloc(NNODES * sizeof(float));
    float* bias512 = (float*)alloc(512 * sizeof(float));
    uint16_t* H    = (uint16_t*)alloc((size_t)NNODES * CDIM * 2);  // h1 / h2
    uint16_t* G    = (uint16_t*)alloc((size_t)NNODES * CDIM * 2);  // lin out
    uint16_t* Vb   = (uint16_t*)alloc((size_t)NNODES * CDIM * 2);  // adjacent to G
    (void)Vb;
    // UV[50000][512] overlays G+Vb (both free at edge-predictor time).
    uint16_t* UV   = G;

    hipMemsetAsync(row_start, 0, (NNODES + 1) * sizeof(int), stream);

    transpose_cvt_kernel<<<dim3(DIN / 32, CDIM / 32), 256, 0, stream>>>(W1, W1t, DIN, CDIM);
    transpose_cvt_kernel<<<dim3(CDIM / 32, CDIM / 32), 256, 0, stream>>>(W2, W2t, CDIM, CDIM);
    transpose_cvt_kernel<<<dim3(CDIM / 32, CDIM / 32), 256, 0, stream>>>(Wp1, WpABt, CDIM, CDIM);
    transpose_cvt_kernel<<<dim3(CDIM / 32, CDIM / 32), 256, 0, stream>>>(Wp1 + CDIM * CDIM, WpABt + CDIM * CDIM, CDIM, CDIM);
    bias512_kernel<<<2, 256, 0, stream>>>(bp1, bias512);

    const int NB = (NNODES + 1 + 1023) / 1024;   // 49
    count_kernel<<<(ELOOP + 255) / 256, 256, 0, stream>>>(ei, row_start);
    scan_part_kernel<<<NB, 1024, 0, stream>>>(row_start, bsum);
    scan_bsum_kernel<<<1, 64, 0, stream>>>(bsum, NB);
    scan_add_kernel<<<NB, 1024, 0, stream>>>(bsum, row_start, cursor);
    fill_kernel<<<(ELOOP + 255) / 256, 256, 0, stream>>>(ei, cursor, csr_src);

    dim3 gg((NNODES + BM - 1) / BM, CDIM / BN);

    // layer 1: h1_lin = x @ W1  (fp32 A path)
    gemm_f32_bt<<<gg, 256, 0, stream>>>(x, W1t, G, NNODES, CDIM, DIN);
    rowdot_kernel<<<NNODES / 4, 256, 0, stream>>>(G, as1, ad1, s_src, s_dst);
    attn_kernel<<<NNODES / 4, 256, 0, stream>>>(row_start, csr_src, s_src, s_dst, G, b1, H);

    // layer 2
    gemm_bt<<<gg, 256, 0, stream>>>(H, W2t, G, nullptr, NNODES, CDIM, CDIM);
    rowdot_kernel<<<NNODES / 4, 256, 0, stream>>>(G, as2, ad2, s_src, s_dst);
    attn_kernel<<<NNODES / 4, 256, 0, stream>>>(row_start, csr_src, s_src, s_dst, G, b2, H);

    // edge predictor: UV = h2 @ [WpA | WpB]  (single N=512 GEMM, bias [bp1,0])
    dim3 gg2((NNODES + BM - 1) / BM, 512 / BN);
    gemm_bt<<<gg2, 256, 0, stream>>>(H, WpABt, UV, bias512, NNODES, 512, CDIM);

    edgepred_kernel<<<NEDGES / 16, 256, 0, stream>>>(ei, UV, wp2, bp2, out);
}

// Round 3
// 1109.455 us; speedup vs baseline: 1.1171x; 1.0332x over previous
//
#include <hip/hip_runtime.h>
#include <hip/hip_bf16.h>
#include <stdint.h>

#define NNODES 50000
#define NEDGES 800000
#define DIN    2048
#define CDIM   256
#define ELOOP  (NEDGES + NNODES)   // edges + self loops

using bf16x8 = __attribute__((ext_vector_type(8))) short;
using f32x4  = __attribute__((ext_vector_type(4))) float;
using gvoid  = __attribute__((address_space(1))) const void;
using lvoid  = __attribute__((address_space(3))) void;

__device__ __forceinline__ float bf2f(uint16_t u) {
    union { uint32_t i; float f; } v; v.i = (uint32_t)u << 16; return v.f;
}
__device__ __forceinline__ uint16_t f2bf(float f) {
    union { float f; uint32_t i; } v; v.f = f;
    uint32_t i = v.i;
    return (uint16_t)((i + 0x7FFFu + ((i >> 16) & 1u)) >> 16);
}

#define BM 128
#define BN 128
#define BK 32

#define WAITVM(N) asm volatile("s_waitcnt vmcnt(" #N ")" ::: "memory")

// Fused rowdot epilogue helper: per-thread partial dots over its 16 columns,
// lm-group shuffle reduce, one atomicAdd per row.
#define ROWDOT_EPILOGUE()                                                     \
    if (s_src) {                                                              \
        float av[4], dv[4];                                                   \
        for (int nt2 = 0; nt2 < 4; ++nt2) {                                   \
            int gn = bn + wn + nt2 * 16 + lm;                                 \
            av[nt2] = asrc[gn];                                               \
            dv[nt2] = adst[gn];                                               \
        }                                                                     \
        for (int mt = 0; mt < 4; ++mt)                                        \
            for (int r = 0; r < 4; ++r) {                                     \
                float ps = 0.f, pd = 0.f;                                     \
                for (int nt2 = 0; nt2 < 4; ++nt2) {                           \
                    float v = acc[mt][nt2][r];                                \
                    ps += v * av[nt2];                                        \
                    pd += v * dv[nt2];                                        \
                }                                                             \
                for (int d = 1; d < 16; d <<= 1) {                            \
                    ps += __shfl_xor(ps, d);                                  \
                    pd += __shfl_xor(pd, d);                                  \
                }                                                             \
                if (lm == 0) {                                                \
                    int gm = bm + wm + mt * 16 + lq * 4 + r;                  \
                    if (gm < M) {                                             \
                        atomicAdd(&s_src[gm], ps);                            \
                        atomicAdd(&s_dst[gm], pd);                            \
                    }                                                         \
                }                                                             \
            }                                                                 \
    }

// ---------------------------------------------------------------- GEMM (bf16 A)
// C[M,N] = A[M,K] @ Bt[N,K]^T ; A,Bt,C bf16 row-major; bias fp32 optional.
// Depth-2 pipeline: 3 LDS buffers, counted vmcnt (4 loads/stage/wave),
// raw s_barrier. Optional fused rowdot (s_src/s_dst accumulated via atomics).
__global__ __launch_bounds__(256)
void gemm_bt(const uint16_t* __restrict__ A, const uint16_t* __restrict__ Bt,
             uint16_t* __restrict__ C, const float* __restrict__ bias,
             const float* __restrict__ asrc, const float* __restrict__ adst,
             float* __restrict__ s_src, float* __restrict__ s_dst,
             int M, int N, int K)
{
    __shared__ __align__(16) uint16_t lA[3][BM * BK];   // 3 x 8 KB
    __shared__ __align__(16) uint16_t lB[3][BN * BK];   // 3 x 8 KB
    const int tid  = threadIdx.x;
    const int wave = tid >> 6;
    const int lane = tid & 63;
    const int lm = lane & 15, lq = lane >> 4;
    const int bm = blockIdx.x * BM;
    const int bn = blockIdx.y * BN;
    const int wm = (wave >> 1) * 64;
    const int wn = (wave & 1) * 64;

    f32x4 acc[4][4];
    for (int i = 0; i < 4; ++i)
        for (int j = 0; j < 4; ++j)
            acc[i][j] = (f32x4)0.0f;

    auto stage = [&](int buf, int k0) {          // 4 global_load_lds per wave
        for (int j = 0; j < 2; ++j) {            // A tile: 512 x 16B chunks
            int c = j * 256 + wave * 64 + lane;
            int row = c >> 2, cc = c & 3;
            int gr = bm + row; if (gr >= M) gr = M - 1;
            const uint16_t* gp = A + (size_t)gr * K + k0 + cc * 8;
            __builtin_amdgcn_global_load_lds((gvoid*)gp,
                (lvoid*)(lA[buf] + (size_t)(j * 256 + wave * 64) * 8), 16, 0, 0);
        }
        for (int j = 0; j < 2; ++j) {            // B tile
            int c = j * 256 + wave * 64 + lane;
            int row = c >> 2, cc = c & 3;
            const uint16_t* gp = Bt + (size_t)(bn + row) * K + k0 + cc * 8;
            __builtin_amdgcn_global_load_lds((gvoid*)gp,
                (lvoid*)(lB[buf] + (size_t)(j * 256 + wave * 64) * 8), 16, 0, 0);
        }
    };

    const int ntiles = K / BK;                   // >= 8 always
    stage(0, 0);
    stage(1, BK);
    WAITVM(4);                                   // tile 0 landed (own 4 oldest)
    __builtin_amdgcn_s_barrier();

    for (int t = 0; t < ntiles; ++t) {
        const int cur = t % 3;
        if (t + 2 < ntiles) stage((t + 2) % 3, (t + 2) * BK);

        bf16x8 af[4], bfr[4];
        for (int mt = 0; mt < 4; ++mt)
            af[mt] = *(const bf16x8*)(lA[cur] + (wm + mt * 16 + lm) * BK + lq * 8);
        for (int nt2 = 0; nt2 < 4; ++nt2)
            bfr[nt2] = *(const bf16x8*)(lB[cur] + (wn + nt2 * 16 + lm) * BK + lq * 8);

        for (int mt = 0; mt < 4; ++mt)
            for (int nt2 = 0; nt2 < 4; ++nt2)
                acc[mt][nt2] = __builtin_amdgcn_mfma_f32_16x16x32_bf16(
                    af[mt], bfr[nt2], acc[mt][nt2], 0, 0, 0);

        if (t + 1 < ntiles) {
            if (t + 2 < ntiles) WAITVM(4);       // tile t+1 done, t+2 in flight
            else                WAITVM(0);       // tail: drain last tile
            __builtin_amdgcn_s_barrier();
        }
    }

    for (int mt = 0; mt < 4; ++mt) {
        for (int nt2 = 0; nt2 < 4; ++nt2) {
            int gn = bn + wn + nt2 * 16 + lm;
            float badd = bias ? bias[gn] : 0.0f;
            for (int r = 0; r < 4; ++r) {
                int gm = bm + wm + mt * 16 + lq * 4 + r;
                if (gm < M)
                    C[(size_t)gm * N + gn] = f2bf(acc[mt][nt2][r] + badd);
            }
        }
    }

    ROWDOT_EPILOGUE();
}

// ---------------------------------------------------------------- GEMM (fp32 A)
// C[M,N] = A_f32[M,K] @ Bt_bf16[N,K]^T ; fp32->bf16 at fragment read via
// v_cvt_pk_bf16_f32 (packed, 2 f32/instr: 16 instrs/iter vs ~160 scalar ops).
// A tile rows are 128 B (bank-period) -> XOR chunk swizzle.
// Depth-2 pipeline (6 loads/stage/wave). Optional fused rowdot.
__global__ __launch_bounds__(256)
void gemm_f32_bt(const float* __restrict__ A, const uint16_t* __restrict__ Bt,
                 uint16_t* __restrict__ C,
                 const float* __restrict__ asrc, const float* __restrict__ adst,
                 float* __restrict__ s_src, float* __restrict__ s_dst,
                 int M, int N, int K)
{
    __shared__ __align__(16) float    lA[3][BM * BK];   // 3 x 16 KB fp32
    __shared__ __align__(16) uint16_t lB[3][BN * BK];   // 3 x 8 KB bf16
    const int tid  = threadIdx.x;
    const int wave = tid >> 6;
    const int lane = tid & 63;
    const int lm = lane & 15, lq = lane >> 4;
    const int bm = blockIdx.x * BM;
    const int bn = blockIdx.y * BN;
    const int wm = (wave >> 1) * 64;
    const int wn = (wave & 1) * 64;

    f32x4 acc[4][4];
    for (int i = 0; i < 4; ++i)
        for (int j = 0; j < 4; ++j)
            acc[i][j] = (f32x4)0.0f;

    auto stage = [&](int buf, int k0) {          // 6 global_load_lds per wave
        for (int j = 0; j < 4; ++j) {            // A fp32: 1024 x 16B, swizzled
            int c = j * 256 + wave * 64 + lane;
            int row = c >> 3;                    // 8 chunks per row
            int lc  = (c & 7) ^ (row & 7);
            int gr = bm + row; if (gr >= M) gr = M - 1;
            const float* gp = A + (size_t)gr * K + k0 + lc * 4;
            __builtin_amdgcn_global_load_lds((gvoid*)gp,
                (lvoid*)(lA[buf] + (size_t)(j * 256 + wave * 64) * 4), 16, 0, 0);
        }
        for (int j = 0; j < 2; ++j) {            // B bf16: 512 x 16B
            int c = j * 256 + wave * 64 + lane;
            int row = c >> 2, cc = c & 3;
            const uint16_t* gp = Bt + (size_t)(bn + row) * K + k0 + cc * 8;
            __builtin_amdgcn_global_load_lds((gvoid*)gp,
                (lvoid*)(lB[buf] + (size_t)(j * 256 + wave * 64) * 8), 16, 0, 0);
        }
    };

    const int ntiles = K / BK;
    stage(0, 0);
    stage(1, BK);
    WAITVM(6);
    __builtin_amdgcn_s_barrier();

    for (int t = 0; t < ntiles; ++t) {
        const int cur = t % 3;
        if (t + 2 < ntiles) stage((t + 2) % 3, (t + 2) * BK);

        bf16x8 af[4], bfr[4];
        for (int mt = 0; mt < 4; ++mt) {
            int r = wm + mt * 16 + lm;
            int s0 = (lq * 2)     ^ (r & 7);
            int s1 = (lq * 2 + 1) ^ (r & 7);
            f32x4 a0 = *(const f32x4*)(lA[cur] + r * BK + s0 * 4);
            f32x4 a1 = *(const f32x4*)(lA[cur] + r * BK + s1 * 4);
            union { uint32_t u[4]; bf16x8 v; } t2;
            float x0 = a0[0], x1 = a0[1], x2 = a0[2], x3 = a0[3];
            float y0 = a1[0], y1 = a1[1], y2 = a1[2], y3 = a1[3];
            asm("v_cvt_pk_bf16_f32 %0, %1, %2" : "=v"(t2.u[0]) : "v"(x0), "v"(x1));
            asm("v_cvt_pk_bf16_f32 %0, %1, %2" : "=v"(t2.u[1]) : "v"(x2), "v"(x3));
            asm("v_cvt_pk_bf16_f32 %0, %1, %2" : "=v"(t2.u[2]) : "v"(y0), "v"(y1));
            asm("v_cvt_pk_bf16_f32 %0, %1, %2" : "=v"(t2.u[3]) : "v"(y2), "v"(y3));
            af[mt] = t2.v;
        }
        for (int nt2 = 0; nt2 < 4; ++nt2)
            bfr[nt2] = *(const bf16x8*)(lB[cur] + (wn + nt2 * 16 + lm) * BK + lq * 8);

        for (int mt = 0; mt < 4; ++mt)
            for (int nt2 = 0; nt2 < 4; ++nt2)
                acc[mt][nt2] = __builtin_amdgcn_mfma_f32_16x16x32_bf16(
                    af[mt], bfr[nt2], acc[mt][nt2], 0, 0, 0);

        if (t + 1 < ntiles) {
            if (t + 2 < ntiles) WAITVM(6);
            else                WAITVM(0);
            __builtin_amdgcn_s_barrier();
        }
    }

    for (int mt = 0; mt < 4; ++mt) {
        for (int nt2 = 0; nt2 < 4; ++nt2) {
            int gn = bn + wn + nt2 * 16 + lm;
            for (int r = 0; r < 4; ++r) {
                int gm = bm + wm + mt * 16 + lq * 4 + r;
                if (gm < M)
                    C[(size_t)gm * N + gn] = f2bf(acc[mt][nt2][r]);
            }
        }
    }

    ROWDOT_EPILOGUE();
}

// ---------------------------------------------------------------- weight prep
// Wt_bf16[n*K + k] = (bf16) W_f32[k*N + n] ; tiled via LDS (coalesced both sides)
__global__ __launch_bounds__(256)
void transpose_cvt_kernel(const float* __restrict__ W,
                          uint16_t* __restrict__ Wt, int K, int N)
{
    __shared__ float tile[32][33];
    const int k0 = blockIdx.x * 32, n0 = blockIdx.y * 32;
    const int tx = threadIdx.x & 31, ty = threadIdx.x >> 5;   // 32x8
    for (int r = 0; r < 32; r += 8)
        tile[ty + r][tx] = W[(size_t)(k0 + ty + r) * N + n0 + tx];
    __syncthreads();
    for (int r = 0; r < 32; r += 8)
        Wt[(size_t)(n0 + ty + r) * K + k0 + tx] = f2bf(tile[tx][ty + r]);
}

// bias512[i] = (i<256) ? bp1[i] : 0
__global__ void bias512_kernel(const float* __restrict__ bp1,
                               float* __restrict__ bias512)
{
    int i = blockIdx.x * 256 + threadIdx.x;
    if (i < 512) bias512[i] = (i < 256) ? bp1[i] : 0.0f;
}

// ---------------------------------------------------------------- CSR build
__global__ void count_kernel(const int* __restrict__ ei, int* __restrict__ rs)
{
    int i = blockIdx.x * 256 + threadIdx.x;
    if (i >= ELOOP) return;
    int dst = (i < NEDGES) ? ei[NEDGES + i] : (i - NEDGES);
    atomicAdd(&rs[dst + 1], 1);
}

// parallel scan over rs[0..NNODES]: 49 blocks x 1024
__global__ __launch_bounds__(1024)
void scan_part_kernel(int* __restrict__ rs, int* __restrict__ bsum)
{
    __shared__ int wsum[16];
    const int b = blockIdx.x, tid = threadIdx.x, lane = tid & 63, w = tid >> 6;
    int i = b * 1024 + tid;
    int v = (i <= NNODES) ? rs[i] : 0;
    int s = v;
    for (int d = 1; d < 64; d <<= 1) {
        int t = __shfl_up(s, d);
        if (lane >= d) s += t;
    }
    if (lane == 63) wsum[w] = s;
    __syncthreads();
    if (tid < 16) {
        int x = wsum[tid];
        for (int d = 1; d < 16; d <<= 1) {
            int t = __shfl_up(x, d);
            if (tid >= d) x += t;
        }
        wsum[tid] = x;
    }
    __syncthreads();
    int incl = s + (w > 0 ? wsum[w - 1] : 0);
    if (i <= NNODES) rs[i] = incl;
    if (tid == 1023) bsum[b] = incl;      // chunk total (padding adds 0)
}

__global__ void scan_bsum_kernel(int* __restrict__ bsum, int nb)
{
    int tid = threadIdx.x;                 // 64 threads, nb <= 64
    int v = (tid < nb) ? bsum[tid] : 0;
    for (int d = 1; d < 64; d <<= 1) {
        int t = __shfl_up(v, d);
        if (tid >= d) v += t;
    }
    if (tid < nb) bsum[tid] = v;           // inclusive block prefix
}

__global__ __launch_bounds__(1024)
void scan_add_kernel(const int* __restrict__ bsum, int* __restrict__ rs,
                     int* __restrict__ cursor)
{
    int b = blockIdx.x;
    int i = b * 1024 + threadIdx.x;
    int add = b ? bsum[b - 1] : 0;
    if (i <= NNODES) {
        int r = rs[i] + add;
        rs[i] = r;
        if (i < NNODES) cursor[i] = r;
    }
}

__global__ void fill_kernel(const int* __restrict__ ei, int* __restrict__ cursor,
                            int* __restrict__ csr_src)
{
    int i = blockIdx.x * 256 + threadIdx.x;
    if (i >= ELOOP) return;
    int src, dst;
    if (i < NEDGES) { src = ei[i]; dst = ei[NEDGES + i]; }
    else            { src = dst = i - NEDGES; }
    int pos = atomicAdd(&cursor[dst], 1);
    csr_src[pos] = src;
}

// ---------------------------------------------------------------- GAT attention
// one node per wave; weighted-gather loop processes 2 edges/iter via 32-lane
// half-waves (16B/lane) -> half the serial chain, 2x gathers in flight.
__global__ __launch_bounds__(256)
void attn_kernel(const int* __restrict__ row_start, const int* __restrict__ csr_src,
                 const float* __restrict__ s_src, const float* __restrict__ s_dst,
                 const uint16_t* __restrict__ g, const float* __restrict__ bvec,
                 uint16_t* __restrict__ hout)
{
    int n = blockIdx.x * 4 + (threadIdx.x >> 6);
    int lane = threadIdx.x & 63;
    int h = lane >> 5, hl = lane & 31;
    int beg = row_start[n], end = row_start[n + 1];
    float sdn = s_dst[n];

    float m = -1e30f;
    for (int i = beg + lane; i < end; i += 64) {
        float e = s_src[csr_src[i]] + sdn;
        e = (e > 0.f) ? e : 0.2f * e;
        m = fmaxf(m, e);
    }
    for (int d = 32; d; d >>= 1) m = fmaxf(m, __shfl_xor(m, d));

    float sum = 0.f;
    for (int i = beg + lane; i < end; i += 64) {
        float e = s_src[csr_src[i]] + sdn;
        e = (e > 0.f) ? e : 0.2f * e;
        sum += __expf(e - m);
    }
    for (int d = 32; d; d >>= 1) sum += __shfl_xor(sum, d);
    float inv = 1.f / (sum + 1e-16f);

    float a0 = 0.f, a1 = 0.f, a2 = 0.f, a3 = 0.f;
    float a4 = 0.f, a5 = 0.f, a6 = 0.f, a7 = 0.f;
    for (int i = beg + h; i < end; i += 2) {
        int src = csr_src[i];
        float e = s_src[src] + sdn;
        e = (e > 0.f) ? e : 0.2f * e;
        float alpha = __expf(e - m) * inv;
        uint4 rv = *(const uint4*)(g + (size_t)src * CDIM + hl * 8);
        a0 += alpha * bf2f((uint16_t)(rv.x & 0xffffu));
        a1 += alpha * bf2f((uint16_t)(rv.x >> 16));
        a2 += alpha * bf2f((uint16_t)(rv.y & 0xffffu));
        a3 += alpha * bf2f((uint16_t)(rv.y >> 16));
        a4 += alpha * bf2f((uint16_t)(rv.z & 0xffffu));
        a5 += alpha * bf2f((uint16_t)(rv.z >> 16));
        a6 += alpha * bf2f((uint16_t)(rv.w & 0xffffu));
        a7 += alpha * bf2f((uint16_t)(rv.w >> 16));
    }
    a0 += __shfl_xor(a0, 32); a1 += __shfl_xor(a1, 32);
    a2 += __shfl_xor(a2, 32); a3 += __shfl_xor(a3, 32);
    a4 += __shfl_xor(a4, 32); a5 += __shfl_xor(a5, 32);
    a6 += __shfl_xor(a6, 32); a7 += __shfl_xor(a7, 32);

    if (h == 0) {
        const float4 b0 = *(const float4*)(bvec + hl * 8);
        const float4 b1 = *(const float4*)(bvec + hl * 8 + 4);
        uint4 o;
        o.x = (uint32_t)f2bf(a0 + b0.x) | ((uint32_t)f2bf(a1 + b0.y) << 16);
        o.y = (uint32_t)f2bf(a2 + b0.z) | ((uint32_t)f2bf(a3 + b0.w) << 16);
        o.z = (uint32_t)f2bf(a4 + b1.x) | ((uint32_t)f2bf(a5 + b1.y) << 16);
        o.w = (uint32_t)f2bf(a6 + b1.z) | ((uint32_t)f2bf(a7 + b1.w) << 16);
        *(uint4*)(hout + (size_t)n * CDIM + hl * 8) = o;
    }
}

// ---------------------------------------------------------------- edge predictor
__global__ __launch_bounds__(256)
void edgepred_kernel(const int* __restrict__ ei,
                     const uint16_t* __restrict__ UV,
                     const float* __restrict__ wp2, const float* __restrict__ bp2,
                     float* __restrict__ out)
{
    const int tid = threadIdx.x;
    const int grp = tid >> 4, l = tid & 15;
    const int e = blockIdx.x * 16 + grp;
    int src = ei[e];
    int dst = ei[NEDGES + e];
    const uint16_t* Up = UV + (size_t)src * 512 + l * 16;
    const uint16_t* Vp = UV + (size_t)dst * 512 + 256 + l * 16;
    const uint4 u0 = *(const uint4*)(Up);
    const uint4 u1 = *(const uint4*)(Up + 8);
    const uint4 v0 = *(const uint4*)(Vp);
    const uint4 v1 = *(const uint4*)(Vp + 8);
    const float4 w0 = *(const float4*)(wp2 + l * 16);
    const float4 w1 = *(const float4*)(wp2 + l * 16 + 4);
    const float4 w2 = *(const float4*)(wp2 + l * 16 + 8);
    const float4 w3 = *(const float4*)(wp2 + l * 16 + 12);
    float acc = 0.f;
    auto proc = [&](uint32_t uu, uint32_t vv, float wa, float wb) {
        float z0 = fmaxf(bf2f((uint16_t)(uu & 0xffffu)) + bf2f((uint16_t)(vv & 0xffffu)), 0.f);
        float z1 = fmaxf(bf2f((uint16_t)(uu >> 16)) + bf2f((uint16_t)(vv >> 16)), 0.f);
        acc += z0 * wa + z1 * wb;
    };
    proc(u0.x, v0.x, w0.x, w0.y); proc(u0.y, v0.y, w0.z, w0.w);
    proc(u0.z, v0.z, w1.x, w1.y); proc(u0.w, v0.w, w1.z, w1.w);
    proc(u1.x, v1.x, w2.x, w2.y); proc(u1.y, v1.y, w2.z, w2.w);
    proc(u1.z, v1.z, w3.x, w3.y); proc(u1.w, v1.w, w3.z, w3.w);
    for (int d = 1; d < 16; d <<= 1) acc += __shfl_xor(acc, d);
    if (l == 0) out[e] = acc + *bp2;
}

// ---------------------------------------------------------------- launch
extern "C" void kernel_launch(void* const* d_in, const int* in_sizes, int n_in,
                              void* d_out, int out_size, void* d_ws, size_t ws_size,
                              hipStream_t stream)
{
    const float* x   = (const float*)d_in[0];
    const int*   ei  = (const int*)d_in[1];
    const float* W1  = (const float*)d_in[2];
    const float* as1 = (const float*)d_in[3];
    const float* ad1 = (const float*)d_in[4];
    const float* b1  = (const float*)d_in[5];
    const float* W2  = (const float*)d_in[6];
    const float* as2 = (const float*)d_in[7];
    const float* ad2 = (const float*)d_in[8];
    const float* b2  = (const float*)d_in[9];
    const float* Wp1 = (const float*)d_in[10];
    const float* bp1 = (const float*)d_in[11];
    const float* wp2 = (const float*)d_in[12];
    const float* bp2 = (const float*)d_in[13];
    float* out = (float*)d_out;

    char* ws = (char*)d_ws;
    size_t off = 0;
    auto alloc = [&](size_t bytes) -> void* {
        void* p = ws + off;
        off += (bytes + 255) & ~(size_t)255;
        return p;
    };
    uint16_t* W1t   = (uint16_t*)alloc((size_t)DIN * CDIM * 2);
    uint16_t* W2t   = (uint16_t*)alloc((size_t)CDIM * CDIM * 2);
    uint16_t* WpABt = (uint16_t*)alloc((size_t)2 * CDIM * CDIM * 2); // 512x256 stacked
    int* row_start = (int*)alloc((NNODES + 1) * sizeof(int));
    int* cursor    = (int*)alloc(NNODES * sizeof(int));
    int* csr_src   = (int*)alloc((size_t)ELOOP * sizeof(int));
    int* bsum      = (int*)alloc(64 * sizeof(int));
    float* sbuf    = (float*)alloc((size_t)2 * NNODES * sizeof(float));
    float* s_src   = sbuf;
    float* s_dst   = sbuf + NNODES;
    float* bias512 = (float*)alloc(512 * sizeof(float));
    uint16_t* H    = (uint16_t*)alloc((size_t)NNODES * CDIM * 2);  // h1 / h2
    uint16_t* G    = (uint16_t*)alloc((size_t)NNODES * CDIM * 2);  // lin out
    uint16_t* Vb   = (uint16_t*)alloc((size_t)NNODES * CDIM * 2);  // adjacent to G
    (void)Vb;
    // UV[50000][512] overlays G+Vb (both free at edge-predictor time).
    uint16_t* UV   = G;

    hipMemsetAsync(row_start, 0, (NNODES + 1) * sizeof(int), stream);
    hipMemsetAsync(sbuf, 0, (size_t)2 * NNODES * sizeof(float), stream);

    transpose_cvt_kernel<<<dim3(DIN / 32, CDIM / 32), 256, 0, stream>>>(W1, W1t, DIN, CDIM);
    transpose_cvt_kernel<<<dim3(CDIM / 32, CDIM / 32), 256, 0, stream>>>(W2, W2t, CDIM, CDIM);
    transpose_cvt_kernel<<<dim3(CDIM / 32, CDIM / 32), 256, 0, stream>>>(Wp1, WpABt, CDIM, CDIM);
    transpose_cvt_kernel<<<dim3(CDIM / 32, CDIM / 32), 256, 0, stream>>>(Wp1 + CDIM * CDIM, WpABt + CDIM * CDIM, CDIM, CDIM);
    bias512_kernel<<<2, 256, 0, stream>>>(bp1, bias512);

    const int NB = (NNODES + 1 + 1023) / 1024;   // 49
    count_kernel<<<(ELOOP + 255) / 256, 256, 0, stream>>>(ei, row_start);
    scan_part_kernel<<<NB, 1024, 0, stream>>>(row_start, bsum);
    scan_bsum_kernel<<<1, 64, 0, stream>>>(bsum, NB);
    scan_add_kernel<<<NB, 1024, 0, stream>>>(bsum, row_start, cursor);
    fill_kernel<<<(ELOOP + 255) / 256, 256, 0, stream>>>(ei, cursor, csr_src);

    dim3 gg((NNODES + BM - 1) / BM, CDIM / BN);

    // layer 1: h1_lin = x @ W1  (fp32 A path, fused rowdot)
    gemm_f32_bt<<<gg, 256, 0, stream>>>(x, W1t, G, as1, ad1, s_src, s_dst,
                                        NNODES, CDIM, DIN);
    attn_kernel<<<NNODES / 4, 256, 0, stream>>>(row_start, csr_src, s_src, s_dst, G, b1, H);

    // layer 2 (fused rowdot; zero accumulators first)
    hipMemsetAsync(sbuf, 0, (size_t)2 * NNODES * sizeof(float), stream);
    gemm_bt<<<gg, 256, 0, stream>>>(H, W2t, G, nullptr, as2, ad2, s_src, s_dst,
                                    NNODES, CDIM, CDIM);
    attn_kernel<<<NNODES / 4, 256, 0, stream>>>(row_start, csr_src, s_src, s_dst, G, b2, H);

    // edge predictor: UV = h2 @ [WpA | WpB]  (single N=512 GEMM, bias [bp1,0])
    dim3 gg2((NNODES + BM - 1) / BM, 512 / BN);
    gemm_bt<<<gg2, 256, 0, stream>>>(H, WpABt, UV, bias512, nullptr, nullptr,
                                     nullptr, nullptr, NNODES, 512, CDIM);

    edgepred_kernel<<<NEDGES / 16, 256, 0, stream>>>(ei, UV, wp2, bp2, out);
}

// Round 5
// 1085.818 us; speedup vs baseline: 1.1414x; 1.0218x over previous
//
#include <hip/hip_runtime.h>
#include <hip/hip_bf16.h>
#include <stdint.h>

#define NNODES 50000
#define NEDGES 800000
#define DIN    2048
#define CDIM   256
#define ELOOP  (NEDGES + NNODES)   // edges + self loops

using bf16x8 = __attribute__((ext_vector_type(8))) short;
using f32x4  = __attribute__((ext_vector_type(4))) float;
using gvoid  = __attribute__((address_space(1))) const void;
using lvoid  = __attribute__((address_space(3))) void;

__device__ __forceinline__ float bf2f(uint16_t u) {
    union { uint32_t i; float f; } v; v.i = (uint32_t)u << 16; return v.f;
}
__device__ __forceinline__ uint16_t f2bf(float f) {
    union { float f; uint32_t i; } v; v.f = f;
    uint32_t i = v.i;
    return (uint16_t)((i + 0x7FFFu + ((i >> 16) & 1u)) >> 16);
}
__device__ __forceinline__ void unpack8(uint4 r, float* f) {
    f[0] = bf2f((uint16_t)(r.x & 0xffffu)); f[1] = bf2f((uint16_t)(r.x >> 16));
    f[2] = bf2f((uint16_t)(r.y & 0xffffu)); f[3] = bf2f((uint16_t)(r.y >> 16));
    f[4] = bf2f((uint16_t)(r.z & 0xffffu)); f[5] = bf2f((uint16_t)(r.z >> 16));
    f[6] = bf2f((uint16_t)(r.w & 0xffffu)); f[7] = bf2f((uint16_t)(r.w >> 16));
}

#define BM 128
#define BN 128
#define BK 32

#define WAITVM(N) asm volatile("s_waitcnt vmcnt(" #N ")" ::: "memory")

// Fused rowdot epilogue helper: per-thread partial dots over its 16 columns,
// lm-group shuffle reduce, one atomicAdd per row.
#define ROWDOT_EPILOGUE()                                                     \
    if (s_src) {                                                              \
        float av[4], dv[4];                                                   \
        for (int nt2 = 0; nt2 < 4; ++nt2) {                                   \
            int gn = bn + wn + nt2 * 16 + lm;                                 \
            av[nt2] = asrc[gn];                                               \
            dv[nt2] = adst[gn];                                               \
        }                                                                     \
        for (int mt = 0; mt < 4; ++mt)                                        \
            for (int r = 0; r < 4; ++r) {                                     \
                float ps = 0.f, pd = 0.f;                                     \
                for (int nt2 = 0; nt2 < 4; ++nt2) {                           \
                    float v = acc[mt][nt2][r];                                \
                    ps += v * av[nt2];                                        \
                    pd += v * dv[nt2];                                        \
                }                                                             \
                for (int d = 1; d < 16; d <<= 1) {                            \
                    ps += __shfl_xor(ps, d);                                  \
                    pd += __shfl_xor(pd, d);                                  \
                }                                                             \
                if (lm == 0) {                                                \
                    int gm = bm + wm + mt * 16 + lq * 4 + r;                  \
                    if (gm < M) {                                             \
                        atomicAdd(&s_src[gm], ps);                            \
                        atomicAdd(&s_dst[gm], pd);                            \
                    }                                                         \
                }                                                             \
            }                                                                 \
    }

// ---------------------------------------------------------------- GEMM (bf16 A)
// C[M,N] = A[M,K] @ Bt[N,K]^T ; A,Bt,C bf16 row-major; bias fp32 optional.
// Depth-2 pipeline: 3 LDS buffers, counted vmcnt (4 loads/stage/wave),
// raw s_barrier. Optional fused rowdot (s_src/s_dst accumulated via atomics).
__global__ __launch_bounds__(256)
void gemm_bt(const uint16_t* __restrict__ A, const uint16_t* __restrict__ Bt,
             uint16_t* __restrict__ C, const float* __restrict__ bias,
             const float* __restrict__ asrc, const float* __restrict__ adst,
             float* __restrict__ s_src, float* __restrict__ s_dst,
             int M, int N, int K)
{
    __shared__ __align__(16) uint16_t lA[3][BM * BK];   // 3 x 8 KB
    __shared__ __align__(16) uint16_t lB[3][BN * BK];   // 3 x 8 KB
    const int tid  = threadIdx.x;
    const int wave = tid >> 6;
    const int lane = tid & 63;
    const int lm = lane & 15, lq = lane >> 4;
    const int bm = blockIdx.x * BM;
    const int bn = blockIdx.y * BN;
    const int wm = (wave >> 1) * 64;
    const int wn = (wave & 1) * 64;

    f32x4 acc[4][4];
    for (int i = 0; i < 4; ++i)
        for (int j = 0; j < 4; ++j)
            acc[i][j] = (f32x4)0.0f;

    auto stage = [&](int buf, int k0) {          // 4 global_load_lds per wave
        for (int j = 0; j < 2; ++j) {            // A tile: 512 x 16B chunks
            int c = j * 256 + wave * 64 + lane;
            int row = c >> 2, cc = c & 3;
            int gr = bm + row; if (gr >= M) gr = M - 1;
            const uint16_t* gp = A + (size_t)gr * K + k0 + cc * 8;
            __builtin_amdgcn_global_load_lds((gvoid*)gp,
                (lvoid*)(lA[buf] + (size_t)(j * 256 + wave * 64) * 8), 16, 0, 0);
        }
        for (int j = 0; j < 2; ++j) {            // B tile
            int c = j * 256 + wave * 64 + lane;
            int row = c >> 2, cc = c & 3;
            const uint16_t* gp = Bt + (size_t)(bn + row) * K + k0 + cc * 8;
            __builtin_amdgcn_global_load_lds((gvoid*)gp,
                (lvoid*)(lB[buf] + (size_t)(j * 256 + wave * 64) * 8), 16, 0, 0);
        }
    };

    const int ntiles = K / BK;                   // >= 8 always
    stage(0, 0);
    stage(1, BK);
    WAITVM(4);                                   // tile 0 landed (own 4 oldest)
    __builtin_amdgcn_s_barrier();

    for (int t = 0; t < ntiles; ++t) {
        const int cur = t % 3;
        if (t + 2 < ntiles) stage((t + 2) % 3, (t + 2) * BK);

        bf16x8 af[4], bfr[4];
        for (int mt = 0; mt < 4; ++mt)
            af[mt] = *(const bf16x8*)(lA[cur] + (wm + mt * 16 + lm) * BK + lq * 8);
        for (int nt2 = 0; nt2 < 4; ++nt2)
            bfr[nt2] = *(const bf16x8*)(lB[cur] + (wn + nt2 * 16 + lm) * BK + lq * 8);

        for (int mt = 0; mt < 4; ++mt)
            for (int nt2 = 0; nt2 < 4; ++nt2)
                acc[mt][nt2] = __builtin_amdgcn_mfma_f32_16x16x32_bf16(
                    af[mt], bfr[nt2], acc[mt][nt2], 0, 0, 0);

        if (t + 1 < ntiles) {
            if (t + 2 < ntiles) WAITVM(4);       // tile t+1 done, t+2 in flight
            else                WAITVM(0);       // tail: drain last tile
            __builtin_amdgcn_s_barrier();
        }
    }

    for (int mt = 0; mt < 4; ++mt) {
        for (int nt2 = 0; nt2 < 4; ++nt2) {
            int gn = bn + wn + nt2 * 16 + lm;
            float badd = bias ? bias[gn] : 0.0f;
            for (int r = 0; r < 4; ++r) {
                int gm = bm + wm + mt * 16 + lq * 4 + r;
                if (gm < M)
                    C[(size_t)gm * N + gn] = f2bf(acc[mt][nt2][r] + badd);
            }
        }
    }

    ROWDOT_EPILOGUE();
}

// ---------------------------------------------------------------- GEMM (fp32 A)
// C[M,N] = A_f32[M,K] @ Bt_bf16[N,K]^T ; fp32->bf16 at fragment read via
// v_cvt_pk_bf16_f32. A tile rows are 128 B (bank-period) -> XOR chunk swizzle.
// Depth-2 pipeline (6 loads/stage/wave). Optional fused rowdot.
__global__ __launch_bounds__(256)
void gemm_f32_bt(const float* __restrict__ A, const uint16_t* __restrict__ Bt,
                 uint16_t* __restrict__ C,
                 const float* __restrict__ asrc, const float* __restrict__ adst,
                 float* __restrict__ s_src, float* __restrict__ s_dst,
                 int M, int N, int K)
{
    __shared__ __align__(16) float    lA[3][BM * BK];   // 3 x 16 KB fp32
    __shared__ __align__(16) uint16_t lB[3][BN * BK];   // 3 x 8 KB bf16
    const int tid  = threadIdx.x;
    const int wave = tid >> 6;
    const int lane = tid & 63;
    const int lm = lane & 15, lq = lane >> 4;
    const int bm = blockIdx.x * BM;
    const int bn = blockIdx.y * BN;
    const int wm = (wave >> 1) * 64;
    const int wn = (wave & 1) * 64;

    f32x4 acc[4][4];
    for (int i = 0; i < 4; ++i)
        for (int j = 0; j < 4; ++j)
            acc[i][j] = (f32x4)0.0f;

    auto stage = [&](int buf, int k0) {          // 6 global_load_lds per wave
        for (int j = 0; j < 4; ++j) {            // A fp32: 1024 x 16B, swizzled
            int c = j * 256 + wave * 64 + lane;
            int row = c >> 3;                    // 8 chunks per row
            int lc  = (c & 7) ^ (row & 7);
            int gr = bm + row; if (gr >= M) gr = M - 1;
            const float* gp = A + (size_t)gr * K + k0 + lc * 4;
            __builtin_amdgcn_global_load_lds((gvoid*)gp,
                (lvoid*)(lA[buf] + (size_t)(j * 256 + wave * 64) * 4), 16, 0, 0);
        }
        for (int j = 0; j < 2; ++j) {            // B bf16: 512 x 16B
            int c = j * 256 + wave * 64 + lane;
            int row = c >> 2, cc = c & 3;
            const uint16_t* gp = Bt + (size_t)(bn + row) * K + k0 + cc * 8;
            __builtin_amdgcn_global_load_lds((gvoid*)gp,
                (lvoid*)(lB[buf] + (size_t)(j * 256 + wave * 64) * 8), 16, 0, 0);
        }
    };

    const int ntiles = K / BK;
    stage(0, 0);
    stage(1, BK);
    WAITVM(6);
    __builtin_amdgcn_s_barrier();

    for (int t = 0; t < ntiles; ++t) {
        const int cur = t % 3;
        if (t + 2 < ntiles) stage((t + 2) % 3, (t + 2) * BK);

        bf16x8 af[4], bfr[4];
        for (int mt = 0; mt < 4; ++mt) {
            int r = wm + mt * 16 + lm;
            int s0 = (lq * 2)     ^ (r & 7);
            int s1 = (lq * 2 + 1) ^ (r & 7);
            f32x4 a0 = *(const f32x4*)(lA[cur] + r * BK + s0 * 4);
            f32x4 a1 = *(const f32x4*)(lA[cur] + r * BK + s1 * 4);
            union { uint32_t u[4]; bf16x8 v; } t2;
            float x0 = a0[0], x1 = a0[1], x2 = a0[2], x3 = a0[3];
            float y0 = a1[0], y1 = a1[1], y2 = a1[2], y3 = a1[3];
            asm("v_cvt_pk_bf16_f32 %0, %1, %2" : "=v"(t2.u[0]) : "v"(x0), "v"(x1));
            asm("v_cvt_pk_bf16_f32 %0, %1, %2" : "=v"(t2.u[1]) : "v"(x2), "v"(x3));
            asm("v_cvt_pk_bf16_f32 %0, %1, %2" : "=v"(t2.u[2]) : "v"(y0), "v"(y1));
            asm("v_cvt_pk_bf16_f32 %0, %1, %2" : "=v"(t2.u[3]) : "v"(y2), "v"(y3));
            af[mt] = t2.v;
        }
        for (int nt2 = 0; nt2 < 4; ++nt2)
            bfr[nt2] = *(const bf16x8*)(lB[cur] + (wn + nt2 * 16 + lm) * BK + lq * 8);

        for (int mt = 0; mt < 4; ++mt)
            for (int nt2 = 0; nt2 < 4; ++nt2)
                acc[mt][nt2] = __builtin_amdgcn_mfma_f32_16x16x32_bf16(
                    af[mt], bfr[nt2], acc[mt][nt2], 0, 0, 0);

        if (t + 1 < ntiles) {
            if (t + 2 < ntiles) WAITVM(6);
            else                WAITVM(0);
            __builtin_amdgcn_s_barrier();
        }
    }

    for (int mt = 0; mt < 4; ++mt) {
        for (int nt2 = 0; nt2 < 4; ++nt2) {
            int gn = bn + wn + nt2 * 16 + lm;
            for (int r = 0; r < 4; ++r) {
                int gm = bm + wm + mt * 16 + lq * 4 + r;
                if (gm < M)
                    C[(size_t)gm * N + gn] = f2bf(acc[mt][nt2][r]);
            }
        }
    }

    ROWDOT_EPILOGUE();
}

// ---------------------------------------------------------------- weight prep
__global__ __launch_bounds__(256)
void transpose_cvt_kernel(const float* __restrict__ W,
                          uint16_t* __restrict__ Wt, int K, int N)
{
    __shared__ float tile[32][33];
    const int k0 = blockIdx.x * 32, n0 = blockIdx.y * 32;
    const int tx = threadIdx.x & 31, ty = threadIdx.x >> 5;   // 32x8
    for (int r = 0; r < 32; r += 8)
        tile[ty + r][tx] = W[(size_t)(k0 + ty + r) * N + n0 + tx];
    __syncthreads();
    for (int r = 0; r < 32; r += 8)
        Wt[(size_t)(n0 + ty + r) * K + k0 + tx] = f2bf(tile[tx][ty + r]);
}

// bias512[i] = (i<256) ? bp1[i] : 0
__global__ void bias512_kernel(const float* __restrict__ bp1,
                               float* __restrict__ bias512)
{
    int i = blockIdx.x * 256 + threadIdx.x;
    if (i < 512) bias512[i] = (i < 256) ? bp1[i] : 0.0f;
}

// ---------------------------------------------------------------- CSR build
__global__ void count_kernel(const int* __restrict__ ei, int* __restrict__ rs)
{
    int i = blockIdx.x * 256 + threadIdx.x;
    if (i >= ELOOP) return;
    int dst = (i < NEDGES) ? ei[NEDGES + i] : (i - NEDGES);
    atomicAdd(&rs[dst + 1], 1);
}

// parallel scan over rs[0..NNODES]: 49 blocks x 1024
__global__ __launch_bounds__(1024)
void scan_part_kernel(int* __restrict__ rs, int* __restrict__ bsum)
{
    __shared__ int wsum[16];
    const int b = blockIdx.x, tid = threadIdx.x, lane = tid & 63, w = tid >> 6;
    int i = b * 1024 + tid;
    int v = (i <= NNODES) ? rs[i] : 0;
    int s = v;
    for (int d = 1; d < 64; d <<= 1) {
        int t = __shfl_up(s, d);
        if (lane >= d) s += t;
    }
    if (lane == 63) wsum[w] = s;
    __syncthreads();
    if (tid < 16) {
        int x = wsum[tid];
        for (int d = 1; d < 16; d <<= 1) {
            int t = __shfl_up(x, d);
            if (tid >= d) x += t;
        }
        wsum[tid] = x;
    }
    __syncthreads();
    int incl = s + (w > 0 ? wsum[w - 1] : 0);
    if (i <= NNODES) rs[i] = incl;
    if (tid == 1023) bsum[b] = incl;      // chunk total (padding adds 0)
}

__global__ void scan_bsum_kernel(int* __restrict__ bsum, int nb)
{
    int tid = threadIdx.x;                 // 64 threads, nb <= 64
    int v = (tid < nb) ? bsum[tid] : 0;
    for (int d = 1; d < 64; d <<= 1) {
        int t = __shfl_up(v, d);
        if (tid >= d) v += t;
    }
    if (tid < nb) bsum[tid] = v;           // inclusive block prefix
}

__global__ __launch_bounds__(1024)
void scan_add_kernel(const int* __restrict__ bsum, int* __restrict__ rs,
                     int* __restrict__ cursor)
{
    int b = blockIdx.x;
    int i = b * 1024 + threadIdx.x;
    int add = b ? bsum[b - 1] : 0;
    if (i <= NNODES) {
        int r = rs[i] + add;
        rs[i] = r;
        if (i < NNODES) cursor[i] = r;
    }
}

__global__ void fill_kernel(const int* __restrict__ ei, int* __restrict__ cursor,
                            int* __restrict__ csr_src, int* __restrict__ csr_eid)
{
    int i = blockIdx.x * 256 + threadIdx.x;
    if (i >= ELOOP) return;
    int src, dst, eid;
    if (i < NEDGES) { src = ei[i]; dst = ei[NEDGES + i]; eid = i; }
    else            { src = dst = i - NEDGES; eid = -1; }
    int pos = atomicAdd(&cursor[dst], 1);
    csr_src[pos] = src;
    csr_eid[pos] = eid;
}

// ---------------------------------------------------------------- GAT attention
// one node per wave; weighted-gather loop processes 4 edges/iter via 16-lane
// quarter-waves (32B/lane) -> serial chain /4, 4x gathers in flight.
__global__ __launch_bounds__(256)
void attn_kernel(const int* __restrict__ row_start, const int* __restrict__ csr_src,
                 const float* __restrict__ s_src, const float* __restrict__ s_dst,
                 const uint16_t* __restrict__ g, const float* __restrict__ bvec,
                 uint16_t* __restrict__ hout)
{
    int n = blockIdx.x * 4 + (threadIdx.x >> 6);
    int lane = threadIdx.x & 63;
    int beg = row_start[n], end = row_start[n + 1];
    float sdn = s_dst[n];

    float m = -1e30f;
    for (int i = beg + lane; i < end; i += 64) {
        float e = s_src[csr_src[i]] + sdn;
        e = (e > 0.f) ? e : 0.2f * e;
        m = fmaxf(m, e);
    }
    for (int d = 32; d; d >>= 1) m = fmaxf(m, __shfl_xor(m, d));

    float sum = 0.f;
    for (int i = beg + lane; i < end; i += 64) {
        float e = s_src[csr_src[i]] + sdn;
        e = (e > 0.f) ? e : 0.2f * e;
        sum += __expf(e - m);
    }
    for (int d = 32; d; d >>= 1) sum += __shfl_xor(sum, d);
    float inv = 1.f / (sum + 1e-16f);

    const int q = lane >> 4, ql = lane & 15;
    float a[16];
    #pragma unroll
    for (int j = 0; j < 16; ++j) a[j] = 0.f;

    for (int i = beg + q; i < end; i += 4) {
        int src = csr_src[i];
        float e = s_src[src] + sdn;
        e = (e > 0.f) ? e : 0.2f * e;
        float alpha = __expf(e - m) * inv;
        const uint16_t* gp = g + (size_t)src * CDIM + ql * 16;
        uint4 r0 = *(const uint4*)gp;
        uint4 r1 = *(const uint4*)(gp + 8);
        float f0[8], f1[8];
        unpack8(r0, f0); unpack8(r1, f1);
        #pragma unroll
        for (int j = 0; j < 8; ++j) {
            a[j]     += alpha * f0[j];
            a[8 + j] += alpha * f1[j];
        }
    }
    #pragma unroll
    for (int j = 0; j < 16; ++j) {
        a[j] += __shfl_xor(a[j], 16);
        a[j] += __shfl_xor(a[j], 32);
    }

    if (q == 0) {
        const float4 b0 = *(const float4*)(bvec + ql * 16);
        const float4 b1 = *(const float4*)(bvec + ql * 16 + 4);
        const float4 b2 = *(const float4*)(bvec + ql * 16 + 8);
        const float4 b3 = *(const float4*)(bvec + ql * 16 + 12);
        uint4 o0, o1;
        o0.x = (uint32_t)f2bf(a[0]  + b0.x) | ((uint32_t)f2bf(a[1]  + b0.y) << 16);
        o0.y = (uint32_t)f2bf(a[2]  + b0.z) | ((uint32_t)f2bf(a[3]  + b0.w) << 16);
        o0.z = (uint32_t)f2bf(a[4]  + b1.x) | ((uint32_t)f2bf(a[5]  + b1.y) << 16);
        o0.w = (uint32_t)f2bf(a[6]  + b1.z) | ((uint32_t)f2bf(a[7]  + b1.w) << 16);
        o1.x = (uint32_t)f2bf(a[8]  + b2.x) | ((uint32_t)f2bf(a[9]  + b2.y) << 16);
        o1.y = (uint32_t)f2bf(a[10] + b2.z) | ((uint32_t)f2bf(a[11] + b2.w) << 16);
        o1.z = (uint32_t)f2bf(a[12] + b3.x) | ((uint32_t)f2bf(a[13] + b3.y) << 16);
        o1.w = (uint32_t)f2bf(a[14] + b3.z) | ((uint32_t)f2bf(a[15] + b3.w) << 16);
        uint16_t* op = hout + (size_t)n * CDIM + ql * 16;
        *(uint4*)op = o0;
        *(uint4*)(op + 8) = o1;
    }
}

// ---------------------------------------------------------------- edge predictor
// dst-CSR form: one node per wave. V[dst] loaded ONCE into registers
// (coalesced); per edge only U[src] is gathered. 2 edges in flight via
// 32-lane half-waves (8 cols/lane). Writes out[eid] (original edge order).
__global__ __launch_bounds__(256)
void edgepred_kernel(const int* __restrict__ row_start,
                     const int* __restrict__ csr_src,
                     const int* __restrict__ csr_eid,
                     const uint16_t* __restrict__ UV,
                     const float* __restrict__ wp2, const float* __restrict__ bp2,
                     float* __restrict__ out)
{
    int n = blockIdx.x * 4 + (threadIdx.x >> 6);
    int lane = threadIdx.x & 63;
    int h = lane >> 5, hl = lane & 31;
    int beg = row_start[n], end = row_start[n + 1];

    // V row for this dst: cols hl*8 .. hl*8+7
    uint4 vv = *(const uint4*)(UV + (size_t)n * 512 + 256 + hl * 8);
    float v[8];
    unpack8(vv, v);
    const float4 wa = *(const float4*)(wp2 + hl * 8);
    const float4 wb = *(const float4*)(wp2 + hl * 8 + 4);
    const float bp = *bp2;

    for (int i = beg + h; i < end; i += 2) {
        int eid = csr_eid[i];
        if (eid < 0) continue;                 // self loop: not a real edge
        int src = csr_src[i];
        uint4 uu = *(const uint4*)(UV + (size_t)src * 512 + hl * 8);
        float u[8];
        unpack8(uu, u);
        float acc;
        {
            float z0 = fmaxf(u[0] + v[0], 0.f), z1 = fmaxf(u[1] + v[1], 0.f);
            float z2 = fmaxf(u[2] + v[2], 0.f), z3 = fmaxf(u[3] + v[3], 0.f);
            float z4 = fmaxf(u[4] + v[4], 0.f), z5 = fmaxf(u[5] + v[5], 0.f);
            float z6 = fmaxf(u[6] + v[6], 0.f), z7 = fmaxf(u[7] + v[7], 0.f);
            acc = z0 * wa.x + z1 * wa.y + z2 * wa.z + z3 * wa.w
                + z4 * wb.x + z5 * wb.y + z6 * wb.z + z7 * wb.w;
        }
        for (int d = 1; d < 32; d <<= 1) acc += __shfl_xor(acc, d);
        if (hl == 0) out[eid] = acc + bp;
    }
}

// ---------------------------------------------------------------- launch
extern "C" void kernel_launch(void* const* d_in, const int* in_sizes, int n_in,
                              void* d_out, int out_size, void* d_ws, size_t ws_size,
                              hipStream_t stream)
{
    const float* x   = (const float*)d_in[0];
    const int*   ei  = (const int*)d_in[1];
    const float* W1  = (const float*)d_in[2];
    const float* as1 = (const float*)d_in[3];
    const float* ad1 = (const float*)d_in[4];
    const float* b1  = (const float*)d_in[5];
    const float* W2  = (const float*)d_in[6];
    const float* as2 = (const float*)d_in[7];
    const float* ad2 = (const float*)d_in[8];
    const float* b2  = (const float*)d_in[9];
    const float* Wp1 = (const float*)d_in[10];
    const float* bp1 = (const float*)d_in[11];
    const float* wp2 = (const float*)d_in[12];
    const float* bp2 = (const float*)d_in[13];
    float* out = (float*)d_out;

    char* ws = (char*)d_ws;
    size_t off = 0;
    auto alloc = [&](size_t bytes) -> void* {
        void* p = ws + off;
        off += (bytes + 255) & ~(size_t)255;
        return p;
    };
    uint16_t* W1t   = (uint16_t*)alloc((size_t)DIN * CDIM * 2);
    uint16_t* W2t   = (uint16_t*)alloc((size_t)CDIM * CDIM * 2);
    uint16_t* WpABt = (uint16_t*)alloc((size_t)2 * CDIM * CDIM * 2); // 512x256 stacked
    int* row_start = (int*)alloc((NNODES + 1) * sizeof(int));
    int* cursor    = (int*)alloc(NNODES * sizeof(int));
    int* csr_src   = (int*)alloc((size_t)ELOOP * sizeof(int));
    int* csr_eid   = (int*)alloc((size_t)ELOOP * sizeof(int));
    int* bsum      = (int*)alloc(64 * sizeof(int));
    float* sbuf    = (float*)alloc((size_t)2 * NNODES * sizeof(float));
    float* s_src   = sbuf;
    float* s_dst   = sbuf + NNODES;
    float* bias512 = (float*)alloc(512 * sizeof(float));
    uint16_t* H    = (uint16_t*)alloc((size_t)NNODES * CDIM * 2);  // h1 / h2
    uint16_t* G    = (uint16_t*)alloc((size_t)NNODES * CDIM * 2);  // lin out
    uint16_t* Vb   = (uint16_t*)alloc((size_t)NNODES * CDIM * 2);  // adjacent to G
    (void)Vb;
    // UV[50000][512] overlays G+Vb (both free at edge-predictor time).
    uint16_t* UV   = G;

    hipMemsetAsync(row_start, 0, (NNODES + 1) * sizeof(int), stream);
    hipMemsetAsync(sbuf, 0, (size_t)2 * NNODES * sizeof(float), stream);

    transpose_cvt_kernel<<<dim3(DIN / 32, CDIM / 32), 256, 0, stream>>>(W1, W1t, DIN, CDIM);
    transpose_cvt_kernel<<<dim3(CDIM / 32, CDIM / 32), 256, 0, stream>>>(W2, W2t, CDIM, CDIM);
    transpose_cvt_kernel<<<dim3(CDIM / 32, CDIM / 32), 256, 0, stream>>>(Wp1, WpABt, CDIM, CDIM);
    transpose_cvt_kernel<<<dim3(CDIM / 32, CDIM / 32), 256, 0, stream>>>(Wp1 + CDIM * CDIM, WpABt + CDIM * CDIM, CDIM, CDIM);
    bias512_kernel<<<2, 256, 0, stream>>>(bp1, bias512);

    const int NB = (NNODES + 1 + 1023) / 1024;   // 49
    count_kernel<<<(ELOOP + 255) / 256, 256, 0, stream>>>(ei, row_start);
    scan_part_kernel<<<NB, 1024, 0, stream>>>(row_start, bsum);
    scan_bsum_kernel<<<1, 64, 0, stream>>>(bsum, NB);
    scan_add_kernel<<<NB, 1024, 0, stream>>>(bsum, row_start, cursor);
    fill_kernel<<<(ELOOP + 255) / 256, 256, 0, stream>>>(ei, cursor, csr_src, csr_eid);

    dim3 gg((NNODES + BM - 1) / BM, CDIM / BN);

    // layer 1: h1_lin = x @ W1  (fp32 A path, fused rowdot)
    gemm_f32_bt<<<gg, 256, 0, stream>>>(x, W1t, G, as1, ad1, s_src, s_dst,
                                        NNODES, CDIM, DIN);
    attn_kernel<<<NNODES / 4, 256, 0, stream>>>(row_start, csr_src, s_src, s_dst, G, b1, H);

    // layer 2 (fused rowdot; zero accumulators first)
    hipMemsetAsync(sbuf, 0, (size_t)2 * NNODES * sizeof(float), stream);
    gemm_bt<<<gg, 256, 0, stream>>>(H, W2t, G, nullptr, as2, ad2, s_src, s_dst,
                                    NNODES, CDIM, CDIM);
    attn_kernel<<<NNODES / 4, 256, 0, stream>>>(row_start, csr_src, s_src, s_dst, G, b2, H);

    // edge predictor: UV = h2 @ [WpA | WpB]  (single N=512 GEMM, bias [bp1,0])
    dim3 gg2((NNODES + BM - 1) / BM, 512 / BN);
    gemm_bt<<<gg2, 256, 0, stream>>>(H, WpABt, UV, bias512, nullptr, nullptr,
                                     nullptr, nullptr, NNODES, 512, CDIM);

    edgepred_kernel<<<NNODES / 4, 256, 0, stream>>>(row_start, csr_src, csr_eid,
                                                    UV, wp2, bp2, out);
}

// Round 6
// 1082.236 us; speedup vs baseline: 1.1452x; 1.0033x over previous
//
#include <hip/hip_runtime.h>
#include <hip/hip_bf16.h>
#include <stdint.h>

#define NNODES 50000
#define NEDGES 800000
#define DIN    2048
#define CDIM   256
#define ELOOP  (NEDGES + NNODES)   // edges + self loops
#define DCAP   96                  // per-wave LDS edge stash capacity

using bf16x8 = __attribute__((ext_vector_type(8))) short;
using f32x4  = __attribute__((ext_vector_type(4))) float;
using gvoid  = __attribute__((address_space(1))) const void;
using lvoid  = __attribute__((address_space(3))) void;

__device__ __forceinline__ float bf2f(uint16_t u) {
    union { uint32_t i; float f; } v; v.i = (uint32_t)u << 16; return v.f;
}
__device__ __forceinline__ uint16_t f2bf(float f) {
    union { float f; uint32_t i; } v; v.f = f;
    uint32_t i = v.i;
    return (uint16_t)((i + 0x7FFFu + ((i >> 16) & 1u)) >> 16);
}
__device__ __forceinline__ void unpack8(uint4 r, float* f) {
    f[0] = bf2f((uint16_t)(r.x & 0xffffu)); f[1] = bf2f((uint16_t)(r.x >> 16));
    f[2] = bf2f((uint16_t)(r.y & 0xffffu)); f[3] = bf2f((uint16_t)(r.y >> 16));
    f[4] = bf2f((uint16_t)(r.z & 0xffffu)); f[5] = bf2f((uint16_t)(r.z >> 16));
    f[6] = bf2f((uint16_t)(r.w & 0xffffu)); f[7] = bf2f((uint16_t)(r.w >> 16));
}

#define BM 128
#define BN 128
#define BK 32

#define WAITVM(N) asm volatile("s_waitcnt vmcnt(" #N ")" ::: "memory")

// Fused rowdot epilogue helper: per-thread partial dots over its 16 columns,
// lm-group shuffle reduce, one atomicAdd per row.
#define ROWDOT_EPILOGUE()                                                     \
    if (s_src) {                                                              \
        float av[4], dv[4];                                                   \
        for (int nt2 = 0; nt2 < 4; ++nt2) {                                   \
            int gn = bn + wn + nt2 * 16 + lm;                                 \
            av[nt2] = asrc[gn];                                               \
            dv[nt2] = adst[gn];                                               \
        }                                                                     \
        for (int mt = 0; mt < 4; ++mt)                                        \
            for (int r = 0; r < 4; ++r) {                                     \
                float ps = 0.f, pd = 0.f;                                     \
                for (int nt2 = 0; nt2 < 4; ++nt2) {                           \
                    float v = acc[mt][nt2][r];                                \
                    ps += v * av[nt2];                                        \
                    pd += v * dv[nt2];                                        \
                }                                                             \
                for (int d = 1; d < 16; d <<= 1) {                            \
                    ps += __shfl_xor(ps, d);                                  \
                    pd += __shfl_xor(pd, d);                                  \
                }                                                             \
                if (lm == 0) {                                                \
                    int gm = bm + wm + mt * 16 + lq * 4 + r;                  \
                    if (gm < M) {                                             \
                        atomicAdd(&s_src[gm], ps);                            \
                        atomicAdd(&s_dst[gm], pd);                            \
                    }                                                         \
                }                                                             \
            }                                                                 \
    }

// ---------------------------------------------------------------- GEMM (bf16 A)
// C[M,N] = A[M,K] @ Bt[N,K]^T ; A,Bt,C bf16 row-major; bias fp32 optional.
// Depth-2 pipeline: 3 LDS buffers, counted vmcnt (4 loads/stage/wave),
// raw s_barrier. Optional fused rowdot (s_src/s_dst accumulated via atomics).
__global__ __launch_bounds__(256)
void gemm_bt(const uint16_t* __restrict__ A, const uint16_t* __restrict__ Bt,
             uint16_t* __restrict__ C, const float* __restrict__ bias,
             const float* __restrict__ asrc, const float* __restrict__ adst,
             float* __restrict__ s_src, float* __restrict__ s_dst,
             int M, int N, int K)
{
    __shared__ __align__(16) uint16_t lA[3][BM * BK];   // 3 x 8 KB
    __shared__ __align__(16) uint16_t lB[3][BN * BK];   // 3 x 8 KB
    const int tid  = threadIdx.x;
    const int wave = tid >> 6;
    const int lane = tid & 63;
    const int lm = lane & 15, lq = lane >> 4;
    const int bm = blockIdx.x * BM;
    const int bn = blockIdx.y * BN;
    const int wm = (wave >> 1) * 64;
    const int wn = (wave & 1) * 64;

    f32x4 acc[4][4];
    for (int i = 0; i < 4; ++i)
        for (int j = 0; j < 4; ++j)
            acc[i][j] = (f32x4)0.0f;

    auto stage = [&](int buf, int k0) {          // 4 global_load_lds per wave
        for (int j = 0; j < 2; ++j) {            // A tile: 512 x 16B chunks
            int c = j * 256 + wave * 64 + lane;
            int row = c >> 2, cc = c & 3;
            int gr = bm + row; if (gr >= M) gr = M - 1;
            const uint16_t* gp = A + (size_t)gr * K + k0 + cc * 8;
            __builtin_amdgcn_global_load_lds((gvoid*)gp,
                (lvoid*)(lA[buf] + (size_t)(j * 256 + wave * 64) * 8), 16, 0, 0);
        }
        for (int j = 0; j < 2; ++j) {            // B tile
            int c = j * 256 + wave * 64 + lane;
            int row = c >> 2, cc = c & 3;
            const uint16_t* gp = Bt + (size_t)(bn + row) * K + k0 + cc * 8;
            __builtin_amdgcn_global_load_lds((gvoid*)gp,
                (lvoid*)(lB[buf] + (size_t)(j * 256 + wave * 64) * 8), 16, 0, 0);
        }
    };

    const int ntiles = K / BK;                   // >= 8 always
    stage(0, 0);
    stage(1, BK);
    WAITVM(4);                                   // tile 0 landed (own 4 oldest)
    __builtin_amdgcn_s_barrier();

    for (int t = 0; t < ntiles; ++t) {
        const int cur = t % 3;
        if (t + 2 < ntiles) stage((t + 2) % 3, (t + 2) * BK);

        bf16x8 af[4], bfr[4];
        for (int mt = 0; mt < 4; ++mt)
            af[mt] = *(const bf16x8*)(lA[cur] + (wm + mt * 16 + lm) * BK + lq * 8);
        for (int nt2 = 0; nt2 < 4; ++nt2)
            bfr[nt2] = *(const bf16x8*)(lB[cur] + (wn + nt2 * 16 + lm) * BK + lq * 8);

        for (int mt = 0; mt < 4; ++mt)
            for (int nt2 = 0; nt2 < 4; ++nt2)
                acc[mt][nt2] = __builtin_amdgcn_mfma_f32_16x16x32_bf16(
                    af[mt], bfr[nt2], acc[mt][nt2], 0, 0, 0);

        if (t + 1 < ntiles) {
            if (t + 2 < ntiles) WAITVM(4);       // tile t+1 done, t+2 in flight
            else                WAITVM(0);       // tail: drain last tile
            __builtin_amdgcn_s_barrier();
        }
    }

    for (int mt = 0; mt < 4; ++mt) {
        for (int nt2 = 0; nt2 < 4; ++nt2) {
            int gn = bn + wn + nt2 * 16 + lm;
            float badd = bias ? bias[gn] : 0.0f;
            for (int r = 0; r < 4; ++r) {
                int gm = bm + wm + mt * 16 + lq * 4 + r;
                if (gm < M)
                    C[(size_t)gm * N + gn] = f2bf(acc[mt][nt2][r] + badd);
            }
        }
    }

    ROWDOT_EPILOGUE();
}

// ---------------------------------------------------------------- GEMM (fp32 A)
// C[M,N] = A_f32[M,K] @ Bt_bf16[N,K]^T ; fp32->bf16 at fragment read via
// v_cvt_pk_bf16_f32. A tile rows are 128 B (bank-period) -> XOR chunk swizzle.
// Depth-2 pipeline (6 loads/stage/wave). Optional fused rowdot.
__global__ __launch_bounds__(256)
void gemm_f32_bt(const float* __restrict__ A, const uint16_t* __restrict__ Bt,
                 uint16_t* __restrict__ C,
                 const float* __restrict__ asrc, const float* __restrict__ adst,
                 float* __restrict__ s_src, float* __restrict__ s_dst,
                 int M, int N, int K)
{
    __shared__ __align__(16) float    lA[3][BM * BK];   // 3 x 16 KB fp32
    __shared__ __align__(16) uint16_t lB[3][BN * BK];   // 3 x 8 KB bf16
    const int tid  = threadIdx.x;
    const int wave = tid >> 6;
    const int lane = tid & 63;
    const int lm = lane & 15, lq = lane >> 4;
    const int bm = blockIdx.x * BM;
    const int bn = blockIdx.y * BN;
    const int wm = (wave >> 1) * 64;
    const int wn = (wave & 1) * 64;

    f32x4 acc[4][4];
    for (int i = 0; i < 4; ++i)
        for (int j = 0; j < 4; ++j)
            acc[i][j] = (f32x4)0.0f;

    auto stage = [&](int buf, int k0) {          // 6 global_load_lds per wave
        for (int j = 0; j < 4; ++j) {            // A fp32: 1024 x 16B, swizzled
            int c = j * 256 + wave * 64 + lane;
            int row = c >> 3;                    // 8 chunks per row
            int lc  = (c & 7) ^ (row & 7);
            int gr = bm + row; if (gr >= M) gr = M - 1;
            const float* gp = A + (size_t)gr * K + k0 + lc * 4;
            __builtin_amdgcn_global_load_lds((gvoid*)gp,
                (lvoid*)(lA[buf] + (size_t)(j * 256 + wave * 64) * 4), 16, 0, 0);
        }
        for (int j = 0; j < 2; ++j) {            // B bf16: 512 x 16B
            int c = j * 256 + wave * 64 + lane;
            int row = c >> 2, cc = c & 3;
            const uint16_t* gp = Bt + (size_t)(bn + row) * K + k0 + cc * 8;
            __builtin_amdgcn_global_load_lds((gvoid*)gp,
                (lvoid*)(lB[buf] + (size_t)(j * 256 + wave * 64) * 8), 16, 0, 0);
        }
    };

    const int ntiles = K / BK;
    stage(0, 0);
    stage(1, BK);
    WAITVM(6);
    __builtin_amdgcn_s_barrier();

    for (int t = 0; t < ntiles; ++t) {
        const int cur = t % 3;
        if (t + 2 < ntiles) stage((t + 2) % 3, (t + 2) * BK);

        bf16x8 af[4], bfr[4];
        for (int mt = 0; mt < 4; ++mt) {
            int r = wm + mt * 16 + lm;
            int s0 = (lq * 2)     ^ (r & 7);
            int s1 = (lq * 2 + 1) ^ (r & 7);
            f32x4 a0 = *(const f32x4*)(lA[cur] + r * BK + s0 * 4);
            f32x4 a1 = *(const f32x4*)(lA[cur] + r * BK + s1 * 4);
            union { uint32_t u[4]; bf16x8 v; } t2;
            float x0 = a0[0], x1 = a0[1], x2 = a0[2], x3 = a0[3];
            float y0 = a1[0], y1 = a1[1], y2 = a1[2], y3 = a1[3];
            asm("v_cvt_pk_bf16_f32 %0, %1, %2" : "=v"(t2.u[0]) : "v"(x0), "v"(x1));
            asm("v_cvt_pk_bf16_f32 %0, %1, %2" : "=v"(t2.u[1]) : "v"(x2), "v"(x3));
            asm("v_cvt_pk_bf16_f32 %0, %1, %2" : "=v"(t2.u[2]) : "v"(y0), "v"(y1));
            asm("v_cvt_pk_bf16_f32 %0, %1, %2" : "=v"(t2.u[3]) : "v"(y2), "v"(y3));
            af[mt] = t2.v;
        }
        for (int nt2 = 0; nt2 < 4; ++nt2)
            bfr[nt2] = *(const bf16x8*)(lB[cur] + (wn + nt2 * 16 + lm) * BK + lq * 8);

        for (int mt = 0; mt < 4; ++mt)
            for (int nt2 = 0; nt2 < 4; ++nt2)
                acc[mt][nt2] = __builtin_amdgcn_mfma_f32_16x16x32_bf16(
                    af[mt], bfr[nt2], acc[mt][nt2], 0, 0, 0);

        if (t + 1 < ntiles) {
            if (t + 2 < ntiles) WAITVM(6);
            else                WAITVM(0);
            __builtin_amdgcn_s_barrier();
        }
    }

    for (int mt = 0; mt < 4; ++mt) {
        for (int nt2 = 0; nt2 < 4; ++nt2) {
            int gn = bn + wn + nt2 * 16 + lm;
            for (int r = 0; r < 4; ++r) {
                int gm = bm + wm + mt * 16 + lq * 4 + r;
                if (gm < M)
                    C[(size_t)gm * N + gn] = f2bf(acc[mt][nt2][r]);
            }
        }
    }

    ROWDOT_EPILOGUE();
}

// ---------------------------------------------------------------- weight prep
// All four transposes in one launch; z selects the matrix.
__global__ __launch_bounds__(256)
void transpose_cvt4_kernel(const float* __restrict__ W1,
                           const float* __restrict__ W2,
                           const float* __restrict__ Wp1,
                           uint16_t* __restrict__ W1t,
                           uint16_t* __restrict__ W2t,
                           uint16_t* __restrict__ WpABt)
{
    __shared__ float tile[32][33];
    const int z = blockIdx.z;
    const float* W; uint16_t* Wt; int K, N;
    if (z == 0)      { W = W1;                Wt = W1t;                K = DIN;  N = CDIM; }
    else if (z == 1) { W = W2;                Wt = W2t;                K = CDIM; N = CDIM; }
    else if (z == 2) { W = Wp1;               Wt = WpABt;              K = CDIM; N = CDIM; }
    else             { W = Wp1 + CDIM * CDIM; Wt = WpABt + CDIM * CDIM; K = CDIM; N = CDIM; }
    const int k0 = blockIdx.x * 32, n0 = blockIdx.y * 32;
    if (k0 >= K) return;
    const int tx = threadIdx.x & 31, ty = threadIdx.x >> 5;   // 32x8
    for (int r = 0; r < 32; r += 8)
        tile[ty + r][tx] = W[(size_t)(k0 + ty + r) * N + n0 + tx];
    __syncthreads();
    for (int r = 0; r < 32; r += 8)
        Wt[(size_t)(n0 + ty + r) * K + k0 + tx] = f2bf(tile[tx][ty + r]);
}

// bias512[i] = (i<256) ? bp1[i] : 0
__global__ void bias512_kernel(const float* __restrict__ bp1,
                               float* __restrict__ bias512)
{
    int i = blockIdx.x * 256 + threadIdx.x;
    if (i < 512) bias512[i] = (i < 256) ? bp1[i] : 0.0f;
}

// ---------------------------------------------------------------- CSR build
__global__ void count_kernel(const int* __restrict__ ei, int* __restrict__ rs)
{
    int i = blockIdx.x * 256 + threadIdx.x;
    if (i >= ELOOP) return;
    int dst = (i < NEDGES) ? ei[NEDGES + i] : (i - NEDGES);
    atomicAdd(&rs[dst + 1], 1);
}

// parallel scan over rs[0..NNODES]: 49 blocks x 1024
__global__ __launch_bounds__(1024)
void scan_part_kernel(int* __restrict__ rs, int* __restrict__ bsum)
{
    __shared__ int wsum[16];
    const int b = blockIdx.x, tid = threadIdx.x, lane = tid & 63, w = tid >> 6;
    int i = b * 1024 + tid;
    int v = (i <= NNODES) ? rs[i] : 0;
    int s = v;
    for (int d = 1; d < 64; d <<= 1) {
        int t = __shfl_up(s, d);
        if (lane >= d) s += t;
    }
    if (lane == 63) wsum[w] = s;
    __syncthreads();
    if (tid < 16) {
        int x = wsum[tid];
        for (int d = 1; d < 16; d <<= 1) {
            int t = __shfl_up(x, d);
            if (tid >= d) x += t;
        }
        wsum[tid] = x;
    }
    __syncthreads();
    int incl = s + (w > 0 ? wsum[w - 1] : 0);
    if (i <= NNODES) rs[i] = incl;
    if (tid == 1023) bsum[b] = incl;      // chunk total (padding adds 0)
}

__global__ void scan_bsum_kernel(int* __restrict__ bsum, int nb)
{
    int tid = threadIdx.x;                 // 64 threads, nb <= 64
    int v = (tid < nb) ? bsum[tid] : 0;
    for (int d = 1; d < 64; d <<= 1) {
        int t = __shfl_up(v, d);
        if (tid >= d) v += t;
    }
    if (tid < nb) bsum[tid] = v;           // inclusive block prefix
}

__global__ __launch_bounds__(1024)
void scan_add_kernel(const int* __restrict__ bsum, int* __restrict__ rs,
                     int* __restrict__ cursor)
{
    int b = blockIdx.x;
    int i = b * 1024 + threadIdx.x;
    int add = b ? bsum[b - 1] : 0;
    if (i <= NNODES) {
        int r = rs[i] + add;
        rs[i] = r;
        if (i < NNODES) cursor[i] = r;
    }
}

__global__ void fill_kernel(const int* __restrict__ ei, int* __restrict__ cursor,
                            int* __restrict__ csr_src, int* __restrict__ csr_eid)
{
    int i = blockIdx.x * 256 + threadIdx.x;
    if (i >= ELOOP) return;
    int src, dst, eid;
    if (i < NEDGES) { src = ei[i]; dst = ei[NEDGES + i]; eid = i; }
    else            { src = dst = i - NEDGES; eid = -1; }
    int pos = atomicAdd(&cursor[dst], 1);
    csr_src[pos] = src;
    csr_eid[pos] = eid;
}

// ---------------------------------------------------------------- GAT attention
// one node per wave. Pass A gathers s_src ONCE per edge, stashes (src,e) in
// LDS (cap DCAP; global fallback beyond). Pass B (denom) is LDS-only.
// Pass C: 8-lane groups, 8 edges in flight, 32 cols (64B) per lane.
__global__ __launch_bounds__(256)
void attn_kernel(const int* __restrict__ row_start, const int* __restrict__ csr_src,
                 const float* __restrict__ s_src, const float* __restrict__ s_dst,
                 const uint16_t* __restrict__ g, const float* __restrict__ bvec,
                 uint16_t* __restrict__ hout)
{
    __shared__ int   lsrc[4][DCAP];
    __shared__ float le[4][DCAP];
    const int w = threadIdx.x >> 6;
    int n = blockIdx.x * 4 + w;
    int lane = threadIdx.x & 63;
    int beg = row_start[n], end = row_start[n + 1];
    int deg = end - beg;
    float sdn = s_dst[n];

    // pass A: single gather of s_src, stash, lane max
    float m = -1e30f;
    for (int idx = lane; idx < deg; idx += 64) {
        int src = csr_src[beg + idx];
        float e = s_src[src] + sdn;
        e = (e > 0.f) ? e : 0.2f * e;
        if (idx < DCAP) { lsrc[w][idx] = src; le[w][idx] = e; }
        m = fmaxf(m, e);
    }
    for (int d = 32; d; d >>= 1) m = fmaxf(m, __shfl_xor(m, d));
    asm volatile("s_waitcnt lgkmcnt(0)" ::: "memory");   // stash visible to wave

    // pass B: denom from LDS
    float sum = 0.f;
    for (int idx = lane; idx < deg; idx += 64) {
        float e;
        if (idx < DCAP) e = le[w][idx];
        else {
            int src = csr_src[beg + idx];
            e = s_src[src] + sdn;
            e = (e > 0.f) ? e : 0.2f * e;
        }
        sum += __expf(e - m);
    }
    for (int d = 32; d; d >>= 1) sum += __shfl_xor(sum, d);
    float inv = 1.f / (sum + 1e-16f);

    // pass C: weighted gather, 8-lane groups
    const int gq = lane >> 3, gl = lane & 7;
    float a[32];
    #pragma unroll
    for (int j = 0; j < 32; ++j) a[j] = 0.f;

    for (int idx = gq; idx < deg; idx += 8) {
        int src; float e;
        if (idx < DCAP) { src = lsrc[w][idx]; e = le[w][idx]; }
        else {
            src = csr_src[beg + idx];
            e = s_src[src] + sdn;
            e = (e > 0.f) ? e : 0.2f * e;
        }
        float alpha = __expf(e - m) * inv;
        const uint16_t* gp = g + (size_t)src * CDIM + gl * 32;
        uint4 r0 = *(const uint4*)gp;
        uint4 r1 = *(const uint4*)(gp + 8);
        uint4 r2 = *(const uint4*)(gp + 16);
        uint4 r3 = *(const uint4*)(gp + 24);
        float f0[8], f1[8], f2[8], f3[8];
        unpack8(r0, f0); unpack8(r1, f1); unpack8(r2, f2); unpack8(r3, f3);
        #pragma unroll
        for (int j = 0; j < 8; ++j) {
            a[j]      += alpha * f0[j];
            a[8 + j]  += alpha * f1[j];
            a[16 + j] += alpha * f2[j];
            a[24 + j] += alpha * f3[j];
        }
    }
    #pragma unroll
    for (int j = 0; j < 32; ++j) {
        a[j] += __shfl_xor(a[j], 8);
        a[j] += __shfl_xor(a[j], 16);
        a[j] += __shfl_xor(a[j], 32);
    }

    if (gq == 0) {
        uint16_t* op = hout + (size_t)n * CDIM + gl * 32;
        #pragma unroll
        for (int blk = 0; blk < 4; ++blk) {
            const float4 ba = *(const float4*)(bvec + gl * 32 + blk * 8);
            const float4 bb = *(const float4*)(bvec + gl * 32 + blk * 8 + 4);
            uint4 o;
            o.x = (uint32_t)f2bf(a[blk*8+0] + ba.x) | ((uint32_t)f2bf(a[blk*8+1] + ba.y) << 16);
            o.y = (uint32_t)f2bf(a[blk*8+2] + ba.z) | ((uint32_t)f2bf(a[blk*8+3] + ba.w) << 16);
            o.z = (uint32_t)f2bf(a[blk*8+4] + bb.x) | ((uint32_t)f2bf(a[blk*8+5] + bb.y) << 16);
            o.w = (uint32_t)f2bf(a[blk*8+6] + bb.z) | ((uint32_t)f2bf(a[blk*8+7] + bb.w) << 16);
            *(uint4*)(op + blk * 8) = o;
        }
    }
}

// ---------------------------------------------------------------- edge predictor
// dst-CSR: one node per wave, V[dst] in registers. 16-lane groups ->
// 4 edges in flight; per edge only U[src] gathered (2 x uint4 per lane).
__global__ __launch_bounds__(256)
void edgepred_kernel(const int* __restrict__ row_start,
                     const int* __restrict__ csr_src,
                     const int* __restrict__ csr_eid,
                     const uint16_t* __restrict__ UV,
                     const float* __restrict__ wp2, const float* __restrict__ bp2,
                     float* __restrict__ out)
{
    int n = blockIdx.x * 4 + (threadIdx.x >> 6);
    int lane = threadIdx.x & 63;
    int q = lane >> 4, ql = lane & 15;
    int beg = row_start[n], end = row_start[n + 1];

    // V row for this dst: cols ql*16 .. +15
    const uint16_t* vp = UV + (size_t)n * 512 + 256 + ql * 16;
    uint4 v0 = *(const uint4*)vp;
    uint4 v1 = *(const uint4*)(vp + 8);
    float v[16];
    unpack8(v0, v); unpack8(v1, v + 8);
    float wv[16];
    #pragma unroll
    for (int j = 0; j < 16; j += 4) {
        float4 wq = *(const float4*)(wp2 + ql * 16 + j);
        wv[j] = wq.x; wv[j+1] = wq.y; wv[j+2] = wq.z; wv[j+3] = wq.w;
    }
    const float bp = *bp2;

    for (int i = beg + q; i < end; i += 4) {
        int eid = csr_eid[i];
        if (eid < 0) continue;                 // self loop: not a real edge
        int src = csr_src[i];
        const uint16_t* up = UV + (size_t)src * 512 + ql * 16;
        uint4 u0 = *(const uint4*)up;
        uint4 u1 = *(const uint4*)(up + 8);
        float u[16];
        unpack8(u0, u); unpack8(u1, u + 8);
        float acc = 0.f;
        #pragma unroll
        for (int j = 0; j < 16; ++j)
            acc += fmaxf(u[j] + v[j], 0.f) * wv[j];
        for (int d = 1; d < 16; d <<= 1) acc += __shfl_xor(acc, d);
        if (ql == 0) out[eid] = acc + bp;
    }
}

// ---------------------------------------------------------------- launch
extern "C" void kernel_launch(void* const* d_in, const int* in_sizes, int n_in,
                              void* d_out, int out_size, void* d_ws, size_t ws_size,
                              hipStream_t stream)
{
    const float* x   = (const float*)d_in[0];
    const int*   ei  = (const int*)d_in[1];
    const float* W1  = (const float*)d_in[2];
    const float* as1 = (const float*)d_in[3];
    const float* ad1 = (const float*)d_in[4];
    const float* b1  = (const float*)d_in[5];
    const float* W2  = (const float*)d_in[6];
    const float* as2 = (const float*)d_in[7];
    const float* ad2 = (const float*)d_in[8];
    const float* b2  = (const float*)d_in[9];
    const float* Wp1 = (const float*)d_in[10];
    const float* bp1 = (const float*)d_in[11];
    const float* wp2 = (const float*)d_in[12];
    const float* bp2 = (const float*)d_in[13];
    float* out = (float*)d_out;

    char* ws = (char*)d_ws;
    size_t off = 0;
    auto alloc = [&](size_t bytes) -> void* {
        void* p = ws + off;
        off += (bytes + 255) & ~(size_t)255;
        return p;
    };
    uint16_t* W1t   = (uint16_t*)alloc((size_t)DIN * CDIM * 2);
    uint16_t* W2t   = (uint16_t*)alloc((size_t)CDIM * CDIM * 2);
    uint16_t* WpABt = (uint16_t*)alloc((size_t)2 * CDIM * CDIM * 2); // 512x256 stacked
    int* row_start = (int*)alloc((NNODES + 1) * sizeof(int));
    int* cursor    = (int*)alloc(NNODES * sizeof(int));
    int* csr_src   = (int*)alloc((size_t)ELOOP * sizeof(int));
    int* csr_eid   = (int*)alloc((size_t)ELOOP * sizeof(int));
    int* bsum      = (int*)alloc(64 * sizeof(int));
    float* sbuf    = (float*)alloc((size_t)2 * NNODES * sizeof(float));
    float* s_src   = sbuf;
    float* s_dst   = sbuf + NNODES;
    float* bias512 = (float*)alloc(512 * sizeof(float));
    uint16_t* H    = (uint16_t*)alloc((size_t)NNODES * CDIM * 2);  // h1 / h2
    uint16_t* G    = (uint16_t*)alloc((size_t)NNODES * CDIM * 2);  // lin out
    uint16_t* Vb   = (uint16_t*)alloc((size_t)NNODES * CDIM * 2);  // adjacent to G
    (void)Vb;
    // UV[50000][512] overlays G+Vb (both free at edge-predictor time).
    uint16_t* UV   = G;

    hipMemsetAsync(row_start, 0, (NNODES + 1) * sizeof(int), stream);
    hipMemsetAsync(sbuf, 0, (size_t)2 * NNODES * sizeof(float), stream);

    transpose_cvt4_kernel<<<dim3(DIN / 32, CDIM / 32, 4), 256, 0, stream>>>(
        W1, W2, Wp1, W1t, W2t, WpABt);
    bias512_kernel<<<2, 256, 0, stream>>>(bp1, bias512);

    const int NB = (NNODES + 1 + 1023) / 1024;   // 49
    count_kernel<<<(ELOOP + 255) / 256, 256, 0, stream>>>(ei, row_start);
    scan_part_kernel<<<NB, 1024, 0, stream>>>(row_start, bsum);
    scan_bsum_kernel<<<1, 64, 0, stream>>>(bsum, NB);
    scan_add_kernel<<<NB, 1024, 0, stream>>>(bsum, row_start, cursor);
    fill_kernel<<<(ELOOP + 255) / 256, 256, 0, stream>>>(ei, cursor, csr_src, csr_eid);

    dim3 gg((NNODES + BM - 1) / BM, CDIM / BN);

    // layer 1: h1_lin = x @ W1  (fp32 A path, fused rowdot)
    gemm_f32_bt<<<gg, 256, 0, stream>>>(x, W1t, G, as1, ad1, s_src, s_dst,
                                        NNODES, CDIM, DIN);
    attn_kernel<<<NNODES / 4, 256, 0, stream>>>(row_start, csr_src, s_src, s_dst, G, b1, H);

    // layer 2 (fused rowdot; zero accumulators first)
    hipMemsetAsync(sbuf, 0, (size_t)2 * NNODES * sizeof(float), stream);
    gemm_bt<<<gg, 256, 0, stream>>>(H, W2t, G, nullptr, as2, ad2, s_src, s_dst,
                                    NNODES, CDIM, CDIM);
    attn_kernel<<<NNODES / 4, 256, 0, stream>>>(row_start, csr_src, s_src, s_dst, G, b2, H);

    // edge predictor: UV = h2 @ [WpA | WpB]  (single N=512 GEMM, bias [bp1,0])
    dim3 gg2((NNODES + BM - 1) / BM, 512 / BN);
    gemm_bt<<<gg2, 256, 0, stream>>>(H, WpABt, UV, bias512, nullptr, nullptr,
                                     nullptr, nullptr, NNODES, 512, CDIM);

    edgepred_kernel<<<NNODES / 4, 256, 0, stream>>>(row_start, csr_src, csr_eid,
                                                    UV, wp2, bp2, out);
}